// Round 1
// baseline (8007.376 us; speedup 1.0000x reference)
//
#include <hip/hip_runtime.h>
#include <math.h>

#define TT   32
#define NB   2048
#define SDIM 256
#define ADIM 64
#define LDIM 128
#define HID  750
#define EIN  320   // SDIM + ADIM
#define DIN  384   // SDIM + LDIM

// ---------------------------------------------------------------------------
// Build encoder concat [state, action] -> cat [NB, EIN]
// ---------------------------------------------------------------------------
__global__ void concat_enc_kernel(const float* __restrict__ state,
                                  const float* __restrict__ action,
                                  float* __restrict__ cat) {
    int i = blockIdx.x * blockDim.x + threadIdx.x;
    if (i >= NB * EIN) return;
    int b = i / EIN, c = i % EIN;
    cat[i] = (c < SDIM) ? state[b * SDIM + c] : action[b * ADIM + (c - SDIM)];
}

// ---------------------------------------------------------------------------
// GEMM (X [NB,K] @ W^T [K,HID] + bias) with constant-input LIF epilogue.
// Input is identical across T, so one GEMM + 32-step scan -> spike bitmask.
// ---------------------------------------------------------------------------
template<int K>
__global__ void gemm_lif_const(const float* __restrict__ X,
                               const float* __restrict__ W,
                               const float* __restrict__ bias,
                               unsigned* __restrict__ out_bits) {
    __shared__ float Xs[16][33];
    __shared__ float Ws[16][33];
    int tid = threadIdx.x;
    int tx = tid & 15, ty = tid >> 4;
    int b0 = blockIdx.y << 4, o0 = blockIdx.x << 4;
    int lrow = tid >> 5, lcol = tid & 31;
    float acc = 0.f;
    for (int k0 = 0; k0 < K; k0 += 32) {
#pragma unroll
        for (int p = 0; p < 2; ++p) {
            int r = lrow + p * 8;
            Xs[r][lcol] = X[(b0 + r) * K + k0 + lcol];
            int orow = o0 + r;
            Ws[r][lcol] = (orow < HID) ? W[orow * K + k0 + lcol] : 0.f;
        }
        __syncthreads();
#pragma unroll
        for (int kk = 0; kk < 32; ++kk)
            acc = fmaf(Xs[ty][kk], Ws[tx][kk], acc);
        __syncthreads();
    }
    int o = o0 + tx, b = b0 + ty;
    if (o < HID) {
        float c = acc + bias[o];
        float v = 0.f;
        unsigned bits = 0u;
#pragma unroll
        for (int t = 0; t < TT; ++t) {
            float h = 0.5f * (v + c);     // v + (x - v)/tau, tau=2
            if (h >= 1.0f) { bits |= (1u << t); v = 0.f; }
            else           { v = h; }
        }
        out_bits[b * HID + o] = bits;
    }
}

// ---------------------------------------------------------------------------
// Per-step GEMM over spike bitmasks + LIF epilogue.
// acc[t] = sum_k spike(b,k,t) * W[o,k];  spikes packed as bit t of uint32.
// ---------------------------------------------------------------------------
__global__ void bit_lif_gemm(const unsigned* __restrict__ in_bits,
                             const float* __restrict__ W,
                             const float* __restrict__ bias,
                             unsigned* __restrict__ out_bits) {
    __shared__ unsigned Bs[16][17];
    __shared__ float    Ws[16][17];
    int tid = threadIdx.x;
    int tx = tid & 15, ty = tid >> 4;
    int b0 = blockIdx.y << 4, o0 = blockIdx.x << 4;
    float acc[TT];
#pragma unroll
    for (int t = 0; t < TT; ++t) acc[t] = 0.f;
    for (int k0 = 0; k0 < HID; k0 += 16) {
        int k = k0 + tx;
        Bs[ty][tx] = (k < HID) ? in_bits[(b0 + ty) * HID + k] : 0u;
        int o = o0 + ty;
        Ws[ty][tx] = (k < HID && o < HID) ? W[o * HID + k] : 0.f;
        __syncthreads();
#pragma unroll
        for (int kk = 0; kk < 16; ++kk) {
            unsigned word = Bs[ty][kk];
            float w = Ws[tx][kk];
#pragma unroll
            for (int t = 0; t < TT; ++t)
                acc[t] = fmaf((float)((word >> t) & 1u), w, acc[t]);
        }
        __syncthreads();
    }
    int o = o0 + tx, b = b0 + ty;
    if (o < HID) {
        float bo = bias[o];
        float v = 0.f;
        unsigned bits = 0u;
#pragma unroll
        for (int t = 0; t < TT; ++t) {
            float h = 0.5f * (v + acc[t] + bo);
            if (h >= 1.0f) { bits |= (1u << t); v = 0.f; }
            else           { v = h; }
        }
        out_bits[b * HID + o] = bits;
    }
}

// ---------------------------------------------------------------------------
// mean / log_std heads: per-step GEMM over z2 bitmasks, max over t of x/tau.
// o in [0,128) -> mean (Wm), o in [128,256) -> log_std (Wls).
// ---------------------------------------------------------------------------
__global__ void head_meanls(const unsigned* __restrict__ in_bits,
                            const float* __restrict__ Wm,
                            const float* __restrict__ bm,
                            const float* __restrict__ Wls,
                            const float* __restrict__ bls,
                            float* __restrict__ mean_ws,
                            float* __restrict__ ls_ws) {
    __shared__ unsigned Bs[16][17];
    __shared__ float    Ws[16][17];
    int tid = threadIdx.x;
    int tx = tid & 15, ty = tid >> 4;
    int b0 = blockIdx.y << 4, o0 = blockIdx.x << 4;
    float acc[TT];
#pragma unroll
    for (int t = 0; t < TT; ++t) acc[t] = 0.f;
    for (int k0 = 0; k0 < HID; k0 += 16) {
        int k = k0 + tx;
        Bs[ty][tx] = (k < HID) ? in_bits[(b0 + ty) * HID + k] : 0u;
        int o = o0 + ty;
        const float* Wrow = (o < LDIM) ? &Wm[o * HID] : &Wls[(o - LDIM) * HID];
        Ws[ty][tx] = (k < HID) ? Wrow[k] : 0.f;
        __syncthreads();
#pragma unroll
        for (int kk = 0; kk < 16; ++kk) {
            unsigned word = Bs[ty][kk];
            float w = Ws[tx][kk];
#pragma unroll
            for (int t = 0; t < TT; ++t)
                acc[t] = fmaf((float)((word >> t) & 1u), w, acc[t]);
        }
        __syncthreads();
    }
    int o = o0 + tx, b = b0 + ty;
    float mx = acc[0];
#pragma unroll
    for (int t = 1; t < TT; ++t) mx = fmaxf(mx, acc[t]);
    float bo = (o < LDIM) ? bm[o] : bls[o - LDIM];
    float val = 0.5f * (mx + bo);
    if (o < LDIM) mean_ws[b * LDIM + o] = val;
    else          ls_ws[b * LDIM + (o - LDIM)] = val;
}

// ---------------------------------------------------------------------------
// latent: std = exp(clip(ls)), zlat = mean + std*eps; emit mean/std to d_out
// and build decoder concat [state, zlat] -> cat_d [NB, DIN]
// ---------------------------------------------------------------------------
__global__ void latent_kernel(const float* __restrict__ mean_ws,
                              const float* __restrict__ ls_ws,
                              const float* __restrict__ eps,
                              const float* __restrict__ state,
                              float* __restrict__ out,
                              float* __restrict__ cat_d) {
    int i = blockIdx.x * blockDim.x + threadIdx.x;
    if (i >= NB * DIN) return;
    int b = i / DIN, c = i % DIN;
    if (c < SDIM) {
        cat_d[i] = state[b * SDIM + c];
    } else {
        int o = c - SDIM;
        float m = mean_ws[b * LDIM + o];
        float l = ls_ws[b * LDIM + o];
        l = fminf(fmaxf(l, -4.0f), 15.0f);
        float s = expf(l);
        cat_d[i] = m + s * eps[b * LDIM + o];
        out[NB * ADIM + b * LDIM + o] = m;
        out[NB * ADIM + NB * LDIM + b * LDIM + o] = s;
    }
}

// ---------------------------------------------------------------------------
// action head: per-step GEMM over d2 bitmasks, u = tanh(max_t(x/tau))
// ---------------------------------------------------------------------------
__global__ void head_u(const unsigned* __restrict__ in_bits,
                       const float* __restrict__ Wd3,
                       const float* __restrict__ bd3,
                       float* __restrict__ out) {
    __shared__ unsigned Bs[16][17];
    __shared__ float    Ws[16][17];
    int tid = threadIdx.x;
    int tx = tid & 15, ty = tid >> 4;
    int b0 = blockIdx.y << 4, o0 = blockIdx.x << 4;
    float acc[TT];
#pragma unroll
    for (int t = 0; t < TT; ++t) acc[t] = 0.f;
    for (int k0 = 0; k0 < HID; k0 += 16) {
        int k = k0 + tx;
        Bs[ty][tx] = (k < HID) ? in_bits[(b0 + ty) * HID + k] : 0u;
        int o = o0 + ty;
        Ws[ty][tx] = (k < HID) ? Wd3[o * HID + k] : 0.f;
        __syncthreads();
#pragma unroll
        for (int kk = 0; kk < 16; ++kk) {
            unsigned word = Bs[ty][kk];
            float w = Ws[tx][kk];
#pragma unroll
            for (int t = 0; t < TT; ++t)
                acc[t] = fmaf((float)((word >> t) & 1u), w, acc[t]);
        }
        __syncthreads();
    }
    int o = o0 + tx, b = b0 + ty;
    float mx = acc[0];
#pragma unroll
    for (int t = 1; t < TT; ++t) mx = fmaxf(mx, acc[t]);
    out[b * ADIM + o] = tanhf(0.5f * (mx + bd3[o]));
}

// ---------------------------------------------------------------------------
extern "C" void kernel_launch(void* const* d_in, const int* in_sizes, int n_in,
                              void* d_out, int out_size, void* d_ws, size_t ws_size,
                              hipStream_t stream) {
    const float* state  = (const float*)d_in[0];
    const float* action = (const float*)d_in[1];
    const float* eps    = (const float*)d_in[2];
    const float* W1  = (const float*)d_in[3];
    const float* b1  = (const float*)d_in[4];
    const float* W2  = (const float*)d_in[5];
    const float* b2  = (const float*)d_in[6];
    const float* Wm  = (const float*)d_in[7];
    const float* bm  = (const float*)d_in[8];
    const float* Wls = (const float*)d_in[9];
    const float* bls = (const float*)d_in[10];
    const float* Wd1 = (const float*)d_in[11];
    const float* bd1 = (const float*)d_in[12];
    const float* Wd2 = (const float*)d_in[13];
    const float* bd2 = (const float*)d_in[14];
    const float* Wd3 = (const float*)d_in[15];
    const float* bd3 = (const float*)d_in[16];
    float* out = (float*)d_out;

    char* ws = (char*)d_ws;
    size_t off = 0;
    auto alloc = [&](size_t bytes) {
        void* p = ws + off;
        off += (bytes + 255) & ~(size_t)255;
        return p;
    };
    unsigned* bits_a  = (unsigned*)alloc((size_t)NB * HID * 4);  // z1 / d1 spikes
    unsigned* bits_b  = (unsigned*)alloc((size_t)NB * HID * 4);  // z2 / d2 spikes
    float*    cat     = (float*)   alloc((size_t)NB * DIN * 4);  // enc concat then dec concat
    float*    mean_ws = (float*)   alloc((size_t)NB * LDIM * 4);
    float*    ls_ws   = (float*)   alloc((size_t)NB * LDIM * 4);

    dim3 blk(256);
    dim3 gBig(47, 128);   // 750/16 -> 47 o-tiles, 2048/16 b-tiles

    concat_enc_kernel<<<(NB * EIN + 255) / 256, blk, 0, stream>>>(state, action, cat);
    gemm_lif_const<EIN><<<gBig, blk, 0, stream>>>(cat, W1, b1, bits_a);
    bit_lif_gemm<<<gBig, blk, 0, stream>>>(bits_a, W2, b2, bits_b);
    head_meanls<<<dim3(16, 128), blk, 0, stream>>>(bits_b, Wm, bm, Wls, bls, mean_ws, ls_ws);
    latent_kernel<<<(NB * DIN + 255) / 256, blk, 0, stream>>>(mean_ws, ls_ws, eps, state, out, cat);
    gemm_lif_const<DIN><<<gBig, blk, 0, stream>>>(cat, Wd1, bd1, bits_a);
    bit_lif_gemm<<<gBig, blk, 0, stream>>>(bits_a, Wd2, bd2, bits_b);
    head_u<<<dim3(4, 128), blk, 0, stream>>>(bits_b, Wd3, bd3, out);
}

// Round 2
// 1479.368 us; speedup vs baseline: 5.4127x; 5.4127x over previous
//
#include <hip/hip_runtime.h>
#include <math.h>

#define TT   32
#define NB   2048
#define SDIM 256
#define ADIM 64
#define LDIM 128
#define HID  750
#define KP   768   // padded K / bits row stride (uint32 words per batch row)
#define EIN  320   // SDIM + ADIM
#define DIN  384   // SDIM + LDIM

typedef float    f32x4 __attribute__((ext_vector_type(4)));
typedef unsigned u32x4 __attribute__((ext_vector_type(4)));

// ---------------------------------------------------------------------------
// v_mfma_f32_16x16x32_bf16 via inline asm (D,A,B,C). A/B: 8 bf16 packed in 4
// VGPRs; C/D: 4 f32. Layout (verified learn_hip m89): C col = lane&15,
// row = (lane>>4)*4 + reg. A: row(M)=lane&15, k = (lane>>4)*8 + e (contig 8).
// B: col(N)=lane&15, k same.
// ---------------------------------------------------------------------------
__device__ inline f32x4 mfma16(u32x4 a, u32x4 b, f32x4 c) {
    asm("v_mfma_f32_16x16x32_bf16 %0, %1, %2, %0" : "+v"(c) : "v"(a), "v"(b));
    return c;
}

// ---------------------------------------------------------------------------
// Split fp32 weights into bf16 hi/lo, padded to KP cols (zeros outside valid).
// ---------------------------------------------------------------------------
__global__ void wsplit(const float* __restrict__ src, int rvalid,
                       unsigned short* __restrict__ dh,
                       unsigned short* __restrict__ dl,
                       int row_off, int rspan) {
    int i = blockIdx.x * blockDim.x + threadIdx.x;
    if (i >= rspan * KP) return;
    int r = i / KP, c = i % KP;
    float v = (r < rvalid && c < HID) ? src[r * HID + c] : 0.f;
    unsigned u = __float_as_uint(v);
    unsigned hb = (u + 0x7FFFu + ((u >> 16) & 1u)) >> 16;
    float hf = __uint_as_float(hb << 16);
    float res = v - hf;
    unsigned u2 = __float_as_uint(res);
    unsigned lb = (u2 + 0x7FFFu + ((u2 >> 16) & 1u)) >> 16;
    size_t di = (size_t)(row_off + r) * KP + c;
    dh[di] = (unsigned short)hb;
    dl[di] = (unsigned short)lb;
}

// ---------------------------------------------------------------------------
// Encoder concat [state, action] -> cat [NB, EIN]
// ---------------------------------------------------------------------------
__global__ void concat_enc_kernel(const float* __restrict__ state,
                                  const float* __restrict__ action,
                                  float* __restrict__ cat) {
    int i = blockIdx.x * blockDim.x + threadIdx.x;
    if (i >= NB * EIN) return;
    int b = i / EIN, c = i % EIN;
    cat[i] = (c < SDIM) ? state[b * SDIM + c] : action[b * ADIM + (c - SDIM)];
}

// ---------------------------------------------------------------------------
// Layer-1: fp32 GEMM (X [NB,K] @ W^T + bias), constant-input LIF -> bitmask.
// Writes padded [NB][KP] layout; zero bits for o in [HID, KP).
// ---------------------------------------------------------------------------
template<int K>
__global__ void gemm_lif_const(const float* __restrict__ X,
                               const float* __restrict__ W,
                               const float* __restrict__ bias,
                               unsigned* __restrict__ out_bits) {
    __shared__ float Xs[16][33];
    __shared__ float Ws[16][33];
    int tid = threadIdx.x;
    int tx = tid & 15, ty = tid >> 4;
    int b0 = blockIdx.y << 4, o0 = blockIdx.x << 4;
    int lrow = tid >> 5, lcol = tid & 31;
    float acc = 0.f;
    for (int k0 = 0; k0 < K; k0 += 32) {
#pragma unroll
        for (int p = 0; p < 2; ++p) {
            int r = lrow + p * 8;
            Xs[r][lcol] = X[(b0 + r) * K + k0 + lcol];
            int orow = o0 + r;
            Ws[r][lcol] = (orow < HID) ? W[orow * K + k0 + lcol] : 0.f;
        }
        __syncthreads();
#pragma unroll
        for (int kk = 0; kk < 32; ++kk)
            acc = fmaf(Xs[ty][kk], Ws[tx][kk], acc);
        __syncthreads();
    }
    int o = o0 + tx, b = b0 + ty;
    unsigned sb = 0u;
    if (o < HID) {
        float c = acc + bias[o];
        float v = 0.f;
#pragma unroll
        for (int t = 0; t < TT; ++t) {
            float h = 0.5f * (v + c);
            if (h >= 1.0f) { sb |= (1u << t); v = 0.f; }
            else           { v = h; }
        }
    }
    out_bits[(size_t)b * KP + o] = sb;
}

// ---------------------------------------------------------------------------
// MFMA bit-GEMM: C[(b,t), o] = sum_k bit_t(bits[b,k]) * W[o,k]  (hi+lo bf16)
// WG = 4 waves; wave w handles b = blockIdx.y*4+w (all 32 t), 64 o-cols.
// EPI 0: LIF scan -> out bitmask [NB][KP]
// EPI 1: mean/log_std heads: max over t, 0.5*(mx+bias) -> o0 (o<128) / o1
// EPI 2: action head: tanh(0.5*(mx+bias)) -> o0[b*64+o]
// ---------------------------------------------------------------------------
template<int EPI>
__global__ __launch_bounds__(256)
void bitgemm(const unsigned* __restrict__ bits,
             const unsigned short* __restrict__ Wh,
             const unsigned short* __restrict__ Wl,
             const float* __restrict__ bias,
             const float* __restrict__ bias2,
             unsigned* __restrict__ obits,
             float* __restrict__ o0,
             float* __restrict__ o1) {
    __shared__ float S[4][32][65];
    const int tid  = threadIdx.x;
    const int wave = tid >> 6, l = tid & 63;
    const int kg   = l >> 4, li = l & 15;
    const int b    = blockIdx.y * 4 + wave;
    const int n0   = blockIdx.x * 64;

    f32x4 acc[2][4] = {};
    const unsigned* bp = bits + (size_t)b * KP + kg * 8;
    const int thi = li + 16;

#pragma unroll 2
    for (int k0 = 0; k0 < KP; k0 += 32) {
        u32x4 w0 = *(const u32x4*)(bp + k0);       // words e=0..3
        u32x4 w1 = *(const u32x4*)(bp + k0 + 4);   // words e=4..7
        u32x4 a0, a1;
        a0.x = (((w0.x >> li) & 1u) | (((w0.y >> li) & 1u) << 16)) * 0x3F80u;
        a0.y = (((w0.z >> li) & 1u) | (((w0.w >> li) & 1u) << 16)) * 0x3F80u;
        a0.z = (((w1.x >> li) & 1u) | (((w1.y >> li) & 1u) << 16)) * 0x3F80u;
        a0.w = (((w1.z >> li) & 1u) | (((w1.w >> li) & 1u) << 16)) * 0x3F80u;
        a1.x = (((w0.x >> thi) & 1u) | (((w0.y >> thi) & 1u) << 16)) * 0x3F80u;
        a1.y = (((w0.z >> thi) & 1u) | (((w0.w >> thi) & 1u) << 16)) * 0x3F80u;
        a1.z = (((w1.x >> thi) & 1u) | (((w1.y >> thi) & 1u) << 16)) * 0x3F80u;
        a1.w = (((w1.z >> thi) & 1u) | (((w1.w >> thi) & 1u) << 16)) * 0x3F80u;
#pragma unroll
        for (int nt = 0; nt < 4; ++nt) {
            size_t roff = (size_t)(n0 + nt * 16 + li) * KP + k0 + kg * 8;
            u32x4 bh = *(const u32x4*)(Wh + roff);
            u32x4 bl = *(const u32x4*)(Wl + roff);
            acc[0][nt] = mfma16(a0, bh, acc[0][nt]);
            acc[0][nt] = mfma16(a0, bl, acc[0][nt]);
            acc[1][nt] = mfma16(a1, bh, acc[1][nt]);
            acc[1][nt] = mfma16(a1, bl, acc[1][nt]);
        }
    }

    // stage C tile to LDS: row t = m*16 + kg*4 + r, col = nt*16 + li
    float (*Sw)[65] = S[wave];
#pragma unroll
    for (int m = 0; m < 2; ++m)
#pragma unroll
        for (int nt = 0; nt < 4; ++nt)
#pragma unroll
            for (int r = 0; r < 4; ++r)
                Sw[m * 16 + kg * 4 + r][nt * 16 + li] = acc[m][nt][r];
    __syncthreads();

    if (EPI == 0) {
        int o = n0 + l;
        float bo = (o < HID) ? bias[o] : 0.f;
        float v = 0.f;
        unsigned sb = 0u;
#pragma unroll
        for (int t = 0; t < TT; ++t) {
            float h = 0.5f * (v + Sw[t][l] + bo);
            if (h >= 1.0f) { sb |= (1u << t); v = 0.f; }
            else           { v = h; }
        }
        obits[(size_t)b * KP + o] = (o < HID) ? sb : 0u;
    } else {
        float mx = -1e30f;
#pragma unroll
        for (int t = 0; t < TT; ++t) mx = fmaxf(mx, Sw[t][l]);
        if (EPI == 1) {
            int o = n0 + l;
            float bo = (o < LDIM) ? bias[o] : bias2[o - LDIM];
            float val = 0.5f * (mx + bo);
            if (o < LDIM) o0[(size_t)b * LDIM + o] = val;
            else          o1[(size_t)b * LDIM + (o - LDIM)] = val;
        } else {
            o0[(size_t)b * ADIM + l] = tanhf(0.5f * (mx + bias[l]));
        }
    }
}

// ---------------------------------------------------------------------------
// latent: std = exp(clip(ls)), zlat = mean + std*eps; write mean/std to d_out
// and build decoder concat [state, zlat] -> cat_d [NB, DIN]
// ---------------------------------------------------------------------------
__global__ void latent_kernel(const float* __restrict__ mean_ws,
                              const float* __restrict__ ls_ws,
                              const float* __restrict__ eps,
                              const float* __restrict__ state,
                              float* __restrict__ out,
                              float* __restrict__ cat_d) {
    int i = blockIdx.x * blockDim.x + threadIdx.x;
    if (i >= NB * DIN) return;
    int b = i / DIN, c = i % DIN;
    if (c < SDIM) {
        cat_d[i] = state[b * SDIM + c];
    } else {
        int o = c - SDIM;
        float m = mean_ws[b * LDIM + o];
        float l = ls_ws[b * LDIM + o];
        l = fminf(fmaxf(l, -4.0f), 15.0f);
        float s = expf(l);
        cat_d[i] = m + s * eps[b * LDIM + o];
        out[NB * ADIM + b * LDIM + o] = m;
        out[NB * ADIM + NB * LDIM + b * LDIM + o] = s;
    }
}

// ---------------------------------------------------------------------------
extern "C" void kernel_launch(void* const* d_in, const int* in_sizes, int n_in,
                              void* d_out, int out_size, void* d_ws, size_t ws_size,
                              hipStream_t stream) {
    const float* state  = (const float*)d_in[0];
    const float* action = (const float*)d_in[1];
    const float* eps    = (const float*)d_in[2];
    const float* W1  = (const float*)d_in[3];
    const float* b1  = (const float*)d_in[4];
    const float* W2  = (const float*)d_in[5];
    const float* b2  = (const float*)d_in[6];
    const float* Wm  = (const float*)d_in[7];
    const float* bm  = (const float*)d_in[8];
    const float* Wls = (const float*)d_in[9];
    const float* bls = (const float*)d_in[10];
    const float* Wd1 = (const float*)d_in[11];
    const float* bd1 = (const float*)d_in[12];
    const float* Wd2 = (const float*)d_in[13];
    const float* bd2 = (const float*)d_in[14];
    const float* Wd3 = (const float*)d_in[15];
    const float* bd3 = (const float*)d_in[16];
    float* out = (float*)d_out;

    char* ws = (char*)d_ws;
    size_t off = 0;
    auto alloc = [&](size_t bytes) {
        void* p = ws + off;
        off += (bytes + 255) & ~(size_t)255;
        return p;
    };
    unsigned*       bits_a  = (unsigned*)      alloc((size_t)NB * KP * 4);
    unsigned*       bits_b  = (unsigned*)      alloc((size_t)NB * KP * 4);
    float*          cat     = (float*)         alloc((size_t)NB * DIN * 4);
    float*          mean_ws = (float*)         alloc((size_t)NB * LDIM * 4);
    float*          ls_ws   = (float*)         alloc((size_t)NB * LDIM * 4);
    unsigned short* Whi2    = (unsigned short*)alloc((size_t)KP * KP * 2);
    unsigned short* Wlo2    = (unsigned short*)alloc((size_t)KP * KP * 2);
    unsigned short* WhiD2   = (unsigned short*)alloc((size_t)KP * KP * 2);
    unsigned short* WloD2   = (unsigned short*)alloc((size_t)KP * KP * 2);
    unsigned short* WhH     = (unsigned short*)alloc((size_t)256 * KP * 2);
    unsigned short* WhL     = (unsigned short*)alloc((size_t)256 * KP * 2);
    unsigned short* WuH     = (unsigned short*)alloc((size_t)64 * KP * 2);
    unsigned short* WuL     = (unsigned short*)alloc((size_t)64 * KP * 2);

    dim3 blk(256);

    // weight prep (bf16 hi/lo splits, padded)
    wsplit<<<(768 * KP + 255) / 256, blk, 0, stream>>>(W2,  HID,  Whi2,  Wlo2,  0,   768);
    wsplit<<<(768 * KP + 255) / 256, blk, 0, stream>>>(Wd2, HID,  WhiD2, WloD2, 0,   768);
    wsplit<<<(128 * KP + 255) / 256, blk, 0, stream>>>(Wm,  LDIM, WhH,   WhL,   0,   128);
    wsplit<<<(128 * KP + 255) / 256, blk, 0, stream>>>(Wls, LDIM, WhH,   WhL,   128, 128);
    wsplit<<<(64  * KP + 255) / 256, blk, 0, stream>>>(Wd3, ADIM, WuH,   WuL,   0,   64);

    // encoder
    concat_enc_kernel<<<(NB * EIN + 255) / 256, blk, 0, stream>>>(state, action, cat);
    gemm_lif_const<EIN><<<dim3(48, 128), blk, 0, stream>>>(cat, W1, b1, bits_a);
    bitgemm<0><<<dim3(12, NB / 4), blk, 0, stream>>>(bits_a, Whi2, Wlo2, b2, nullptr,
                                                     bits_b, nullptr, nullptr);
    bitgemm<1><<<dim3(4, NB / 4), blk, 0, stream>>>(bits_b, WhH, WhL, bm, bls,
                                                    nullptr, mean_ws, ls_ws);
    latent_kernel<<<(NB * DIN + 255) / 256, blk, 0, stream>>>(mean_ws, ls_ws, eps, state, out, cat);

    // decoder
    gemm_lif_const<DIN><<<dim3(48, 128), blk, 0, stream>>>(cat, Wd1, bd1, bits_a);
    bitgemm<0><<<dim3(12, NB / 4), blk, 0, stream>>>(bits_a, WhiD2, WloD2, bd2, nullptr,
                                                     bits_b, nullptr, nullptr);
    bitgemm<2><<<dim3(1, NB / 4), blk, 0, stream>>>(bits_b, WuH, WuL, bd3, nullptr,
                                                    nullptr, out, nullptr);
}

// Round 3
// 468.317 us; speedup vs baseline: 17.0982x; 3.1589x over previous
//
#include <hip/hip_runtime.h>
#include <math.h>

#define TT   32
#define NB   2048
#define SDIM 256
#define ADIM 64
#define LDIM 128
#define HID  750
#define KP   768   // padded K / bits row stride (uint32 words per batch row)
#define KC   (KP/8)  // 96 k-chunks of 8
#define EIN  320   // SDIM + ADIM
#define DIN  384   // SDIM + LDIM
#define NSTEP 12   // KP / 64

typedef float    f32x4 __attribute__((ext_vector_type(4)));
typedef unsigned u32x4 __attribute__((ext_vector_type(4)));

// ---------------------------------------------------------------------------
// v_mfma_f32_16x16x32_bf16. A: row=lane&15, k=(lane>>4)*8+e. B: col=lane&15.
// C/D: col=lane&15, row=(lane>>4)*4+reg. (verified R2: absmax 0.0)
// ---------------------------------------------------------------------------
__device__ __forceinline__ f32x4 mfma16(u32x4 a, u32x4 b, f32x4 c) {
    asm("v_mfma_f32_16x16x32_bf16 %0, %1, %2, %0" : "+v"(c) : "v"(a), "v"(b));
    return c;
}

__device__ __forceinline__ void gload_lds16(void* lds, const void* g) {
    __builtin_amdgcn_global_load_lds(
        (const __attribute__((address_space(1))) unsigned int*)g,
        (__attribute__((address_space(3))) unsigned int*)lds, 16, 0, 0);
}

__device__ __forceinline__ unsigned pk2(unsigned u, unsigned v, unsigned s) {
    return (((u >> s) & 1u) | (((v >> s) & 1u) << 16)) * 0x3F80u;
}

// ---------------------------------------------------------------------------
// Split fp32 weights into bf16 hi/lo in k-chunk-major packed layout:
// idx = ((o>>6)*KC + (k>>3))*512 + (o&63)*8 + (k&7), o = o_base + r.
// Rows r >= rvalid and cols k >= HID are zero-padded.
// ---------------------------------------------------------------------------
__global__ void wsplit(const float* __restrict__ src, int rvalid,
                       unsigned short* __restrict__ dh,
                       unsigned short* __restrict__ dl,
                       int o_base, int rspan) {
    int i = blockIdx.x * blockDim.x + threadIdx.x;
    if (i >= rspan * KP) return;
    int r = i / KP, k = i % KP;
    float v = (r < rvalid && k < HID) ? src[r * HID + k] : 0.f;
    unsigned u = __float_as_uint(v);
    unsigned hb = (u + 0x7FFFu + ((u >> 16) & 1u)) >> 16;
    float hf = __uint_as_float(hb << 16);
    float res = v - hf;
    unsigned u2 = __float_as_uint(res);
    unsigned lb = (u2 + 0x7FFFu + ((u2 >> 16) & 1u)) >> 16;
    int o = o_base + r;
    size_t di = (size_t)((o >> 6) * KC + (k >> 3)) * 512 + (o & 63) * 8 + (k & 7);
    dh[di] = (unsigned short)hb;
    dl[di] = (unsigned short)lb;
}

// ---------------------------------------------------------------------------
// Encoder concat [state, action] -> cat [NB, EIN]
// ---------------------------------------------------------------------------
__global__ void concat_enc_kernel(const float* __restrict__ state,
                                  const float* __restrict__ action,
                                  float* __restrict__ cat) {
    int i = blockIdx.x * blockDim.x + threadIdx.x;
    if (i >= NB * EIN) return;
    int b = i / EIN, c = i % EIN;
    cat[i] = (c < SDIM) ? state[b * SDIM + c] : action[b * ADIM + (c - SDIM)];
}

// ---------------------------------------------------------------------------
// Layer-1: fp32 GEMM + constant-input LIF -> bitmask [NB][KP] (pad bits 0).
// ---------------------------------------------------------------------------
template<int K>
__global__ void gemm_lif_const(const float* __restrict__ X,
                               const float* __restrict__ W,
                               const float* __restrict__ bias,
                               unsigned* __restrict__ out_bits) {
    __shared__ float Xs[16][33];
    __shared__ float Ws[16][33];
    int tid = threadIdx.x;
    int tx = tid & 15, ty = tid >> 4;
    int b0 = blockIdx.y << 4, o0 = blockIdx.x << 4;
    int lrow = tid >> 5, lcol = tid & 31;
    float acc = 0.f;
    for (int k0 = 0; k0 < K; k0 += 32) {
#pragma unroll
        for (int p = 0; p < 2; ++p) {
            int r = lrow + p * 8;
            Xs[r][lcol] = X[(b0 + r) * K + k0 + lcol];
            int orow = o0 + r;
            Ws[r][lcol] = (orow < HID) ? W[orow * K + k0 + lcol] : 0.f;
        }
        __syncthreads();
#pragma unroll
        for (int kk = 0; kk < 32; ++kk)
            acc = fmaf(Xs[ty][kk], Ws[tx][kk], acc);
        __syncthreads();
    }
    int o = o0 + tx, b = b0 + ty;
    unsigned sb = 0u;
    if (o < HID) {
        float c = acc + bias[o];
        float v = 0.f;
#pragma unroll
        for (int t = 0; t < TT; ++t) {
            float h = 0.5f * (v + c);
            if (h >= 1.0f) { sb |= (1u << t); v = 0.f; }
            else           { v = h; }
        }
    }
    out_bits[(size_t)b * KP + o] = sb;
}

// ---------------------------------------------------------------------------
// LDS-staged MFMA bit-GEMM.
// Block: 256 thr = 4 waves. Tile: M=256 rows (8 b x 32 t), N=64 cols.
// Wave w: rows [w*64, w*64+64) = 2 b, all 64 cols. K-step 64, double-buffered
// LDS B-tile (hi 8KB + lo 8KB per buf), staged via global_load_lds from the
// pre-packed k-chunk-major weight arrays (linear copy == desired layout).
// EPI 0: LIF -> bits; EPI 1: mean/log_std heads; EPI 2: tanh action head.
// ---------------------------------------------------------------------------
template<int EPI>
__global__ __launch_bounds__(256)
void bitgemm(const unsigned* __restrict__ bits,
             const unsigned short* __restrict__ Wh,
             const unsigned short* __restrict__ Wl,
             const float* __restrict__ bias,
             const float* __restrict__ bias2,
             unsigned* __restrict__ obits,
             float* __restrict__ o0,
             float* __restrict__ o1) {
    __shared__ __align__(16) char smraw[34816];   // 2 bufs x 16KB B-tile | 256x34 f32 epi
    const int tid  = threadIdx.x;
    const int wave = tid >> 6, l = tid & 63;
    const int kg   = l >> 4, li = l & 15;
    const int nb   = blockIdx.x;               // N-block (64 cols)
    const int n0   = nb * 64;
    const int by   = blockIdx.y;               // M-block (8 b)
    const int bb   = by * 8 + wave * 2;        // wave's first batch row

    f32x4 acc[4][4] = {};

    // stage K-step `step` into buffer `buf`
    auto stage = [&](int buf, int step) {
        const unsigned short* sH = Wh + (size_t)(nb * KC + step * 8) * 512;
        const unsigned short* sL = Wl + (size_t)(nb * KC + step * 8) * 512;
        char* dH = smraw + buf * 16384;
        char* dL = dH + 8192;
#pragma unroll
        for (int j = 0; j < 2; ++j) {
            gload_lds16(dH + tid * 16 + j * 4096, sH + tid * 8 + j * 2048);
            gload_lds16(dL + tid * 16 + j * 4096, sL + tid * 8 + j * 2048);
        }
    };

    int cur = 0;
    stage(0, 0);
    __syncthreads();

    for (int step = 0; step < NSTEP; ++step) {
        if (step + 1 < NSTEP) stage(cur ^ 1, step + 1);
        const char* bufB = smraw + cur * 16384;
#pragma unroll
        for (int kh = 0; kh < 2; ++kh) {
            u32x4 wA[2][2];
#pragma unroll
            for (int pb = 0; pb < 2; ++pb) {
                const unsigned* bp = bits + (size_t)(bb + pb) * KP
                                   + step * 64 + kh * 32 + kg * 8;
                wA[pb][0] = *(const u32x4*)bp;
                wA[pb][1] = *(const u32x4*)(bp + 4);
            }
            u32x4 af[4];
#pragma unroll
            for (int pb = 0; pb < 2; ++pb)
#pragma unroll
                for (int th = 0; th < 2; ++th) {
                    unsigned s = li + th * 16;
                    u32x4 a;
                    a.x = pk2(wA[pb][0].x, wA[pb][0].y, s);
                    a.y = pk2(wA[pb][0].z, wA[pb][0].w, s);
                    a.z = pk2(wA[pb][1].x, wA[pb][1].y, s);
                    a.w = pk2(wA[pb][1].z, wA[pb][1].w, s);
                    af[pb * 2 + th] = a;
                }
#pragma unroll
            for (int nt = 0; nt < 4; ++nt) {
                int boff = (((kh * 4 + kg) * 64) + nt * 16 + li) << 4;
                u32x4 bhv = *(const u32x4*)(bufB + boff);
                u32x4 blv = *(const u32x4*)(bufB + 8192 + boff);
#pragma unroll
                for (int mt = 0; mt < 4; ++mt) {
                    acc[mt][nt] = mfma16(af[mt], bhv, acc[mt][nt]);
                    acc[mt][nt] = mfma16(af[mt], blv, acc[mt][nt]);
                }
            }
        }
        __syncthreads();
        cur ^= 1;
    }

    // Epilogue: two 32-col passes through LDS [256 rows][34]
    float* Sf = (float*)smraw;
#pragma unroll
    for (int p = 0; p < 2; ++p) {
#pragma unroll
        for (int mt = 0; mt < 4; ++mt)
#pragma unroll
            for (int ntl = 0; ntl < 2; ++ntl)
#pragma unroll
                for (int r = 0; r < 4; ++r)
                    Sf[(wave * 64 + mt * 16 + kg * 4 + r) * 34 + ntl * 16 + li]
                        = acc[mt][p * 2 + ntl][r];
        __syncthreads();

        int lb = tid >> 5, col = tid & 31;
        int o = n0 + p * 32 + col;
        int b = by * 8 + lb;
        if (EPI == 0) {
            float bo = (o < HID) ? bias[o] : 0.f;
            float v = 0.f;
            unsigned sb = 0u;
#pragma unroll
            for (int t = 0; t < TT; ++t) {
                float h = 0.5f * (v + Sf[(lb * 32 + t) * 34 + col] + bo);
                if (h >= 1.0f) { sb |= (1u << t); v = 0.f; }
                else           { v = h; }
            }
            obits[(size_t)b * KP + o] = (o < HID) ? sb : 0u;
        } else {
            float mx = -1e30f;
#pragma unroll
            for (int t = 0; t < TT; ++t)
                mx = fmaxf(mx, Sf[(lb * 32 + t) * 34 + col]);
            if (EPI == 1) {
                float bo = (o < LDIM) ? bias[o] : bias2[o - LDIM];
                float val = 0.5f * (mx + bo);
                if (o < LDIM) o0[(size_t)b * LDIM + o] = val;
                else          o1[(size_t)b * LDIM + (o - LDIM)] = val;
            } else {
                o0[(size_t)b * ADIM + o] = tanhf(0.5f * (mx + bias[o]));
            }
        }
        __syncthreads();
    }
}

// ---------------------------------------------------------------------------
// latent: std = exp(clip(ls)), zlat = mean + std*eps; write mean/std to d_out
// and build decoder concat [state, zlat] -> cat_d [NB, DIN]
// ---------------------------------------------------------------------------
__global__ void latent_kernel(const float* __restrict__ mean_ws,
                              const float* __restrict__ ls_ws,
                              const float* __restrict__ eps,
                              const float* __restrict__ state,
                              float* __restrict__ out,
                              float* __restrict__ cat_d) {
    int i = blockIdx.x * blockDim.x + threadIdx.x;
    if (i >= NB * DIN) return;
    int b = i / DIN, c = i % DIN;
    if (c < SDIM) {
        cat_d[i] = state[b * SDIM + c];
    } else {
        int o = c - SDIM;
        float m = mean_ws[b * LDIM + o];
        float l = ls_ws[b * LDIM + o];
        l = fminf(fmaxf(l, -4.0f), 15.0f);
        float s = expf(l);
        cat_d[i] = m + s * eps[b * LDIM + o];
        out[NB * ADIM + b * LDIM + o] = m;
        out[NB * ADIM + NB * LDIM + b * LDIM + o] = s;
    }
}

// ---------------------------------------------------------------------------
extern "C" void kernel_launch(void* const* d_in, const int* in_sizes, int n_in,
                              void* d_out, int out_size, void* d_ws, size_t ws_size,
                              hipStream_t stream) {
    const float* state  = (const float*)d_in[0];
    const float* action = (const float*)d_in[1];
    const float* eps    = (const float*)d_in[2];
    const float* W1  = (const float*)d_in[3];
    const float* b1  = (const float*)d_in[4];
    const float* W2  = (const float*)d_in[5];
    const float* b2  = (const float*)d_in[6];
    const float* Wm  = (const float*)d_in[7];
    const float* bm  = (const float*)d_in[8];
    const float* Wls = (const float*)d_in[9];
    const float* bls = (const float*)d_in[10];
    const float* Wd1 = (const float*)d_in[11];
    const float* bd1 = (const float*)d_in[12];
    const float* Wd2 = (const float*)d_in[13];
    const float* bd2 = (const float*)d_in[14];
    const float* Wd3 = (const float*)d_in[15];
    const float* bd3 = (const float*)d_in[16];
    float* out = (float*)d_out;

    char* ws = (char*)d_ws;
    size_t off = 0;
    auto alloc = [&](size_t bytes) {
        void* p = ws + off;
        off += (bytes + 255) & ~(size_t)255;
        return p;
    };
    unsigned*       bits_a  = (unsigned*)      alloc((size_t)NB * KP * 4);
    unsigned*       bits_b  = (unsigned*)      alloc((size_t)NB * KP * 4);
    float*          cat     = (float*)         alloc((size_t)NB * DIN * 4);
    float*          mean_ws = (float*)         alloc((size_t)NB * LDIM * 4);
    float*          ls_ws   = (float*)         alloc((size_t)NB * LDIM * 4);
    unsigned short* Whi2    = (unsigned short*)alloc((size_t)KP * KP * 2);
    unsigned short* Wlo2    = (unsigned short*)alloc((size_t)KP * KP * 2);
    unsigned short* WhiD2   = (unsigned short*)alloc((size_t)KP * KP * 2);
    unsigned short* WloD2   = (unsigned short*)alloc((size_t)KP * KP * 2);
    unsigned short* WhH     = (unsigned short*)alloc((size_t)256 * KP * 2);
    unsigned short* WhL     = (unsigned short*)alloc((size_t)256 * KP * 2);
    unsigned short* WuH     = (unsigned short*)alloc((size_t)64 * KP * 2);
    unsigned short* WuL     = (unsigned short*)alloc((size_t)64 * KP * 2);

    dim3 blk(256);

    // weight prep: bf16 hi/lo split into k-chunk-major packed layout
    wsplit<<<(768 * KP + 255) / 256, blk, 0, stream>>>(W2,  HID,  Whi2,  Wlo2,  0,   768);
    wsplit<<<(768 * KP + 255) / 256, blk, 0, stream>>>(Wd2, HID,  WhiD2, WloD2, 0,   768);
    wsplit<<<(128 * KP + 255) / 256, blk, 0, stream>>>(Wm,  LDIM, WhH,   WhL,   0,   128);
    wsplit<<<(128 * KP + 255) / 256, blk, 0, stream>>>(Wls, LDIM, WhH,   WhL,   128, 128);
    wsplit<<<(64  * KP + 255) / 256, blk, 0, stream>>>(Wd3, ADIM, WuH,   WuL,   0,   64);

    // encoder
    concat_enc_kernel<<<(NB * EIN + 255) / 256, blk, 0, stream>>>(state, action, cat);
    gemm_lif_const<EIN><<<dim3(48, 128), blk, 0, stream>>>(cat, W1, b1, bits_a);
    bitgemm<0><<<dim3(12, NB / 8), blk, 0, stream>>>(bits_a, Whi2, Wlo2, b2, nullptr,
                                                     bits_b, nullptr, nullptr);
    bitgemm<1><<<dim3(4, NB / 8), blk, 0, stream>>>(bits_b, WhH, WhL, bm, bls,
                                                    nullptr, mean_ws, ls_ws);
    latent_kernel<<<(NB * DIN + 255) / 256, blk, 0, stream>>>(mean_ws, ls_ws, eps, state, out, cat);

    // decoder
    gemm_lif_const<DIN><<<dim3(48, 128), blk, 0, stream>>>(cat, Wd1, bd1, bits_a);
    bitgemm<0><<<dim3(12, NB / 8), blk, 0, stream>>>(bits_a, WhiD2, WloD2, bd2, nullptr,
                                                     bits_b, nullptr, nullptr);
    bitgemm<2><<<dim3(1, NB / 8), blk, 0, stream>>>(bits_b, WuH, WuL, bd3, nullptr,
                                                    nullptr, out, nullptr);
}

// Round 4
// 376.340 us; speedup vs baseline: 21.2770x; 1.2444x over previous
//
#include <hip/hip_runtime.h>
#include <math.h>

#define TT   32
#define NB   2048
#define SDIM 256
#define ADIM 64
#define LDIM 128
#define HID  750
#define KP   768    // padded neuron count (k-dim of layer-2 GEMMs)
#define KW   24     // KP/32 words per (b,t) row in transposed bit layout
#define EIN  320    // SDIM + ADIM
#define DIN  384    // SDIM + LDIM
#define NSTEP 12    // KP / 64

typedef float    f32x4 __attribute__((ext_vector_type(4)));
typedef int      i32x4 __attribute__((ext_vector_type(4)));
typedef unsigned u32x4 __attribute__((ext_vector_type(4)));

// v_mfma_f32_16x16x32_bf16: A row=lane&15, k=(lane>>4)*8+e; B col=lane&15;
// C/D col=lane&15, row=(lane>>4)*4+reg.  (verified R2/R3: absmax 0.0)
__device__ __forceinline__ f32x4 mfma16(u32x4 a, u32x4 b, f32x4 c) {
    asm("v_mfma_f32_16x16x32_bf16 %0, %1, %2, %0" : "+v"(c) : "v"(a), "v"(b));
    return c;
}
// v_mfma_i32_16x16x64_i8: same pattern, 16 i8/lane, k=(lane>>4)*16+e (by analogy).
__device__ __forceinline__ i32x4 mfma_i8(u32x4 a, u32x4 b, i32x4 c) {
    asm("v_mfma_i32_16x16x64_i8 %0, %1, %2, %0" : "+v"(c) : "v"(a), "v"(b));
    return c;
}

__device__ __forceinline__ void gload_lds16(void* lds, const void* g) {
    __builtin_amdgcn_global_load_lds(
        (const __attribute__((address_space(1))) unsigned int*)g,
        (__attribute__((address_space(3))) unsigned int*)lds, 16, 0, 0);
}

// ---------------------------------------------------------------------------
// Weight quant to 2-limb i8 (Wq = rint(W*2^19) = hi*256+lo), packed per
// (nb,kstep) 4KB block: off = kg*1024 + (o&63)*16 + (k&15); linear
// global_load_lds copy reproduces the LDS layout the MFMA B-fragment reads.
// ---------------------------------------------------------------------------
__global__ void wsplit_i8(const float* __restrict__ src, int rvalid,
                          char* __restrict__ dh, char* __restrict__ dl,
                          int o_base, int rspan) {
    int i = blockIdx.x * blockDim.x + threadIdx.x;
    if (i >= rspan * KP) return;
    int r = i / KP, k = i % KP;
    float v = (r < rvalid && k < HID) ? src[r * HID + k] : 0.f;
    int q = (int)rintf(v * 524288.f);
    int lo = (q << 24) >> 24;           // sext low byte
    int hi = (q - lo) >> 8;
    int o = o_base + r;
    size_t di = (size_t)((o >> 6) * NSTEP + (k >> 6)) * 4096
              + ((k >> 4) & 3) * 1024 + (o & 63) * 16 + (k & 15);
    dh[di] = (char)hi;
    dl[di] = (char)lo;
}

// ---------------------------------------------------------------------------
// Layer-1 weights: bf16 hi/lo split, packed per (nb,ks) 8KB block:
// elem = (kc*4+kg)*512 + (o&63)*8 + (k&7).
// ---------------------------------------------------------------------------
__global__ void wsplit_bf(const float* __restrict__ src, int K, int KS,
                          unsigned short* __restrict__ dh,
                          unsigned short* __restrict__ dl) {
    int i = blockIdx.x * blockDim.x + threadIdx.x;
    if (i >= KP * K) return;
    int r = i / K, k = i % K;
    float v = (r < HID) ? src[r * K + k] : 0.f;
    unsigned u = __float_as_uint(v);
    unsigned hb = (u + 0x7FFFu + ((u >> 16) & 1u)) >> 16;
    float res = v - __uint_as_float(hb << 16);
    unsigned u2 = __float_as_uint(res);
    unsigned lb = (u2 + 0x7FFFu + ((u2 >> 16) & 1u)) >> 16;
    size_t di = ((size_t)((r >> 6) * KS + (k >> 6)) * 8
               + ((k >> 5) & 1) * 4 + ((k >> 3) & 3)) * 512 + (r & 63) * 8 + (k & 7);
    dh[di] = (unsigned short)hb;
    dl[di] = (unsigned short)lb;
}

// ---------------------------------------------------------------------------
// Activations: bf16 hi/lo split, A-fragment order: idx = ((k>>3)*NB + r)*8 + (k&7)
// ---------------------------------------------------------------------------
__global__ void xsplit(const float* __restrict__ X, int K,
                       unsigned short* __restrict__ dh,
                       unsigned short* __restrict__ dl) {
    int i = blockIdx.x * blockDim.x + threadIdx.x;
    if (i >= NB * K) return;
    int r = i / K, k = i % K;
    float v = X[i];
    unsigned u = __float_as_uint(v);
    unsigned hb = (u + 0x7FFFu + ((u >> 16) & 1u)) >> 16;
    float res = v - __uint_as_float(hb << 16);
    unsigned u2 = __float_as_uint(res);
    unsigned lb = (u2 + 0x7FFFu + ((u2 >> 16) & 1u)) >> 16;
    size_t di = ((size_t)(k >> 3) * NB + r) * 8 + (k & 7);
    dh[di] = (unsigned short)hb;
    dl[di] = (unsigned short)lb;
}

__global__ void concat_enc_kernel(const float* __restrict__ state,
                                  const float* __restrict__ action,
                                  float* __restrict__ cat) {
    int i = blockIdx.x * blockDim.x + threadIdx.x;
    if (i >= NB * EIN) return;
    int b = i / EIN, c = i % EIN;
    cat[i] = (c < SDIM) ? state[b * SDIM + c] : action[b * ADIM + (c - SDIM)];
}

// ---------------------------------------------------------------------------
// Layer-1: bf16 3-product MFMA GEMM (AhBh + AhBl + AlBh) + const-input LIF
// scan + ballot bit-transpose -> bitsT[b][t][kw].
// Block: 4 waves, M=128 batch rows (wave: 32), N=64, K-step 64.
// ---------------------------------------------------------------------------
template<int KS>
__global__ __launch_bounds__(256, 2)
void lif1(const unsigned short* __restrict__ Ah,
          const unsigned short* __restrict__ Al,
          const unsigned short* __restrict__ Wh,
          const unsigned short* __restrict__ Wl,
          const float* __restrict__ bias,
          unsigned* __restrict__ obitsT) {
    __shared__ __align__(16) char smraw[65536];  // loop: 2x16KB | epi: Sb[128][64] u32
    const int tid = threadIdx.x, wave = tid >> 6, l = tid & 63;
    const int kg = l >> 4, li = l & 15;
    const int nb = blockIdx.x, n0 = nb * 64, mb = blockIdx.y;
    const int r0 = mb * 128 + wave * 32;
    f32x4 acc[2][4] = {};

    auto stage = [&](int buf, int step) {
        const char* sH = (const char*)(Wh + (size_t)(nb * KS + step) * 4096);
        const char* sL = (const char*)(Wl + (size_t)(nb * KS + step) * 4096);
        char* d = smraw + buf * 16384;
#pragma unroll
        for (int j = 0; j < 2; ++j) {
            gload_lds16(d + j * 4096 + tid * 16, sH + j * 4096 + tid * 16);
            gload_lds16(d + 8192 + j * 4096 + tid * 16, sL + j * 4096 + tid * 16);
        }
    };

    int cur = 0;
    stage(0, 0);
    __syncthreads();
    for (int step = 0; step < KS; ++step) {
        if (step + 1 < KS) stage(cur ^ 1, step + 1);
        const char* bufB = smraw + cur * 16384;
#pragma unroll
        for (int kc = 0; kc < 2; ++kc) {
            u32x4 ah[2], al2[2];
#pragma unroll
            for (int mt = 0; mt < 2; ++mt) {
                int r = r0 + mt * 16 + li;
                size_t aoff = ((size_t)(step * 8 + kc * 4 + kg) * NB + r) * 8;
                ah[mt]  = *(const u32x4*)(Ah + aoff);
                al2[mt] = *(const u32x4*)(Al + aoff);
            }
#pragma unroll
            for (int nt = 0; nt < 4; ++nt) {
                int boff = (kc * 4 + kg) * 1024 + (nt * 16 + li) * 16;
                u32x4 bh = *(const u32x4*)(bufB + boff);
                u32x4 bl = *(const u32x4*)(bufB + 8192 + boff);
#pragma unroll
                for (int mt = 0; mt < 2; ++mt) {
                    acc[mt][nt] = mfma16(ah[mt], bh, acc[mt][nt]);
                    acc[mt][nt] = mfma16(ah[mt], bl, acc[mt][nt]);
                    acc[mt][nt] = mfma16(al2[mt], bh, acc[mt][nt]);
                }
            }
        }
        __syncthreads();
        cur ^= 1;
    }

    // per-element constant-input LIF scan -> spike word; stash in LDS
    unsigned* Sb = (unsigned*)smraw;  // [128][64]
#pragma unroll
    for (int nt = 0; nt < 4; ++nt) {
        int o = n0 + nt * 16 + li;
        float bo = (o < HID) ? bias[o] : 0.f;
#pragma unroll
        for (int mt = 0; mt < 2; ++mt)
#pragma unroll
            for (int r = 0; r < 4; ++r) {
                float c = acc[mt][nt][r] + bo;
                float v = 0.f;
                unsigned sb = 0u;
#pragma unroll
                for (int t = 0; t < TT; ++t) {
                    float h = 0.5f * (v + c);
                    if (h >= 1.0f) { sb |= (1u << t); v = 0.f; }
                    else           { v = h; }
                }
                Sb[(wave * 32 + mt * 16 + kg * 4 + r) * 64 + nt * 16 + li] = sb;
            }
    }
    __syncthreads();

    // ballot transpose: rows [wave*32, wave*32+32)
    for (int rr = 0; rr < 32; ++rr) {
        int row = wave * 32 + rr;
        unsigned wv = Sb[row * 64 + l];
        unsigned myw = 0;
#pragma unroll
        for (int t = 0; t < TT; ++t) {
            unsigned long long m = __ballot((wv >> t) & 1u);
            if ((l & 31) == t) myw = (l < 32) ? (unsigned)m : (unsigned)(m >> 32);
        }
        int b = mb * 128 + row;
        obitsT[((size_t)b * TT + (l & 31)) * KW + nb * 2 + (l >= 32)] = myw;
    }
}

// ---------------------------------------------------------------------------
// i8 MFMA bit-GEMM over transposed spike bits.
// Block: 4 waves; tile M=256 (8 b x 32 t; wave: 2 b), N=64, K-step 64.
// acc = hi-limb and lo-limb i32; combine (hi<<8)+lo, scale 2^-19.
// EPI 0: LIF scan -> ballot transpose -> obitsT
// EPI 1: mean/log_std heads (max over t)   EPI 2: tanh action head
// ---------------------------------------------------------------------------
template<int EPI>
__global__ __launch_bounds__(256, 2)
void bitgemm(const unsigned* __restrict__ bitsT,
             const char* __restrict__ Wh,
             const char* __restrict__ Wl,
             const float* __restrict__ bias,
             const float* __restrict__ bias2,
             unsigned* __restrict__ obitsT,
             float* __restrict__ o0,
             float* __restrict__ o1) {
    __shared__ __align__(16) char smraw[34816];  // loop: 2x8KB | epi: [256][34] f32
    const int tid = threadIdx.x;
    const int wave = tid >> 6, l = tid & 63;
    const int kg = l >> 4, li = l & 15;
    const int nb = blockIdx.x, n0 = nb * 64;
    const int by = blockIdx.y;
    const int bb = by * 8 + wave * 2;

    i32x4 acc[4][4][2] = {};

    auto stage = [&](int buf, int step) {
        const char* sH = Wh + (size_t)(nb * NSTEP + step) * 4096;
        const char* sL = Wl + (size_t)(nb * NSTEP + step) * 4096;
        char* d = smraw + buf * 8192;
        gload_lds16(d + tid * 16, sH + tid * 16);
        gload_lds16(d + 4096 + tid * 16, sL + tid * 16);
    };

    // A-word index for (mt, step): b = bb + (mt>>1), t = (mt&1)*16 + li
    auto aidx = [&](int mt, int step) -> size_t {
        int b = bb + (mt >> 1);
        int t = (mt & 1) * 16 + li;
        return ((size_t)b * TT + t) * KW + step * 2 + (kg >> 1);
    };

    unsigned aw[4], awn[4];
#pragma unroll
    for (int mt = 0; mt < 4; ++mt) aw[mt] = bitsT[aidx(mt, 0)];

    int cur = 0;
    stage(0, 0);
    __syncthreads();

    for (int step = 0; step < NSTEP; ++step) {
        if (step + 1 < NSTEP) {
            stage(cur ^ 1, step + 1);
#pragma unroll
            for (int mt = 0; mt < 4; ++mt) awn[mt] = bitsT[aidx(mt, step + 1)];
        }
        const char* bufB = smraw + cur * 8192;
        const unsigned fld = (kg & 1) * 16;
        u32x4 afrag[4];
#pragma unroll
        for (int mt = 0; mt < 4; ++mt) {
            unsigned w = aw[mt] >> fld;
            u32x4 a;
#pragma unroll
            for (int j = 0; j < 4; ++j) {
                unsigned x = (w >> (4 * j)) & 0xFu;
                a[j] = (x * 0x00204081u) & 0x01010101u;
            }
            afrag[mt] = a;
        }
#pragma unroll
        for (int nt = 0; nt < 4; ++nt) {
            int boff = kg * 1024 + (nt * 16 + li) * 16;
            u32x4 bh = *(const u32x4*)(bufB + boff);
            u32x4 bl = *(const u32x4*)(bufB + 4096 + boff);
#pragma unroll
            for (int mt = 0; mt < 4; ++mt) {
                acc[mt][nt][0] = mfma_i8(afrag[mt], bh, acc[mt][nt][0]);
                acc[mt][nt][1] = mfma_i8(afrag[mt], bl, acc[mt][nt][1]);
            }
        }
        __syncthreads();
#pragma unroll
        for (int mt = 0; mt < 4; ++mt) aw[mt] = awn[mt];
        cur ^= 1;
    }

    // epilogue: combine limbs, 2 passes of 32 cols through LDS [256][34]
    float* Sf = (float*)smraw;
#pragma unroll
    for (int p = 0; p < 2; ++p) {
#pragma unroll
        for (int mt = 0; mt < 4; ++mt)
#pragma unroll
            for (int ntl = 0; ntl < 2; ++ntl) {
                int nt = p * 2 + ntl;
#pragma unroll
                for (int r = 0; r < 4; ++r) {
                    int cmb = (acc[mt][nt][0][r] << 8) + acc[mt][nt][1][r];
                    Sf[(wave * 64 + mt * 16 + kg * 4 + r) * 34 + ntl * 16 + li]
                        = (float)cmb * (1.f / 524288.f);
                }
            }
        __syncthreads();

        int lb = tid >> 5, col = tid & 31;
        int o = n0 + p * 32 + col;
        int b = by * 8 + lb;
        if (EPI == 0) {
            float bo = (o < HID) ? bias[o] : 0.f;
            float v = 0.f;
            unsigned sb = 0u;
#pragma unroll
            for (int t = 0; t < TT; ++t) {
                float h = 0.5f * (v + Sf[(lb * 32 + t) * 34 + col] + bo);
                if (h >= 1.0f) { sb |= (1u << t); v = 0.f; }
                else           { v = h; }
            }
            if (o >= HID) sb = 0u;
            // ballot transpose within wave (lanes 0..31: b_even, 32..63: b_odd)
            unsigned myw = 0;
#pragma unroll
            for (int t = 0; t < TT; ++t) {
                unsigned long long m = __ballot((sb >> t) & 1u);
                if ((l & 31) == t) myw = (l < 32) ? (unsigned)m : (unsigned)(m >> 32);
            }
            int bw = by * 8 + wave * 2 + (l >= 32);
            obitsT[((size_t)bw * TT + (l & 31)) * KW + nb * 2 + p] = myw;
        } else {
            float mx = -1e30f;
#pragma unroll
            for (int t = 0; t < TT; ++t)
                mx = fmaxf(mx, Sf[(lb * 32 + t) * 34 + col]);
            if (EPI == 1) {
                float bo = (o < LDIM) ? bias[o] : bias2[o - LDIM];
                float val = 0.5f * (mx + bo);
                if (o < LDIM) o0[(size_t)b * LDIM + o] = val;
                else          o1[(size_t)b * LDIM + (o - LDIM)] = val;
            } else {
                o0[(size_t)b * ADIM + o] = tanhf(0.5f * (mx + bias[o]));
            }
        }
        __syncthreads();
    }
}

// ---------------------------------------------------------------------------
__global__ void latent_kernel(const float* __restrict__ mean_ws,
                              const float* __restrict__ ls_ws,
                              const float* __restrict__ eps,
                              const float* __restrict__ state,
                              float* __restrict__ out,
                              float* __restrict__ cat_d) {
    int i = blockIdx.x * blockDim.x + threadIdx.x;
    if (i >= NB * DIN) return;
    int b = i / DIN, c = i % DIN;
    if (c < SDIM) {
        cat_d[i] = state[b * SDIM + c];
    } else {
        int o = c - SDIM;
        float m = mean_ws[b * LDIM + o];
        float l = ls_ws[b * LDIM + o];
        l = fminf(fmaxf(l, -4.0f), 15.0f);
        float s = expf(l);
        cat_d[i] = m + s * eps[b * LDIM + o];
        out[NB * ADIM + b * LDIM + o] = m;
        out[NB * ADIM + NB * LDIM + b * LDIM + o] = s;
    }
}

// ---------------------------------------------------------------------------
extern "C" void kernel_launch(void* const* d_in, const int* in_sizes, int n_in,
                              void* d_out, int out_size, void* d_ws, size_t ws_size,
                              hipStream_t stream) {
    const float* state  = (const float*)d_in[0];
    const float* action = (const float*)d_in[1];
    const float* eps    = (const float*)d_in[2];
    const float* W1  = (const float*)d_in[3];
    const float* b1  = (const float*)d_in[4];
    const float* W2  = (const float*)d_in[5];
    const float* b2  = (const float*)d_in[6];
    const float* Wm  = (const float*)d_in[7];
    const float* bm  = (const float*)d_in[8];
    const float* Wls = (const float*)d_in[9];
    const float* bls = (const float*)d_in[10];
    const float* Wd1 = (const float*)d_in[11];
    const float* bd1 = (const float*)d_in[12];
    const float* Wd2 = (const float*)d_in[13];
    const float* bd2 = (const float*)d_in[14];
    const float* Wd3 = (const float*)d_in[15];
    const float* bd3 = (const float*)d_in[16];
    float* out = (float*)d_out;

    char* ws = (char*)d_ws;
    size_t off = 0;
    auto alloc = [&](size_t bytes) {
        void* p = ws + off;
        off += (bytes + 255) & ~(size_t)255;
        return p;
    };
    unsigned*       bitsT_a = (unsigned*)alloc((size_t)NB * TT * KW * 4);
    unsigned*       bitsT_b = (unsigned*)alloc((size_t)NB * TT * KW * 4);
    float*          cat     = (float*)   alloc((size_t)NB * DIN * 4);
    float*          mean_ws = (float*)   alloc((size_t)NB * LDIM * 4);
    float*          ls_ws   = (float*)   alloc((size_t)NB * LDIM * 4);
    unsigned short* Xh      = (unsigned short*)alloc((size_t)NB * DIN * 2);
    unsigned short* Xl      = (unsigned short*)alloc((size_t)NB * DIN * 2);
    char*           W2h     = (char*)alloc((size_t)KP * KP);
    char*           W2l     = (char*)alloc((size_t)KP * KP);
    char*           Wd2h    = (char*)alloc((size_t)KP * KP);
    char*           Wd2l    = (char*)alloc((size_t)KP * KP);
    char*           WmlsH   = (char*)alloc((size_t)256 * KP);
    char*           WmlsL   = (char*)alloc((size_t)256 * KP);
    char*           Wu3h    = (char*)alloc((size_t)64 * KP);
    char*           Wu3l    = (char*)alloc((size_t)64 * KP);
    unsigned short* W1h     = (unsigned short*)alloc((size_t)KP * EIN * 2);
    unsigned short* W1l     = (unsigned short*)alloc((size_t)KP * EIN * 2);
    unsigned short* Wd1h    = (unsigned short*)alloc((size_t)KP * DIN * 2);
    unsigned short* Wd1l    = (unsigned short*)alloc((size_t)KP * DIN * 2);

    dim3 blk(256);

    // weight prep
    wsplit_i8<<<(KP * KP + 255) / 256, blk, 0, stream>>>(W2,  HID,  W2h,  W2l,  0,   KP);
    wsplit_i8<<<(KP * KP + 255) / 256, blk, 0, stream>>>(Wd2, HID,  Wd2h, Wd2l, 0,   KP);
    wsplit_i8<<<(128 * KP + 255) / 256, blk, 0, stream>>>(Wm,  LDIM, WmlsH, WmlsL, 0,   128);
    wsplit_i8<<<(128 * KP + 255) / 256, blk, 0, stream>>>(Wls, LDIM, WmlsH, WmlsL, 128, 128);
    wsplit_i8<<<(64 * KP + 255) / 256, blk, 0, stream>>>(Wd3, ADIM, Wu3h, Wu3l, 0, 64);
    wsplit_bf<<<(KP * EIN + 255) / 256, blk, 0, stream>>>(W1,  EIN, 5, W1h,  W1l);
    wsplit_bf<<<(KP * DIN + 255) / 256, blk, 0, stream>>>(Wd1, DIN, 6, Wd1h, Wd1l);

    // encoder
    concat_enc_kernel<<<(NB * EIN + 255) / 256, blk, 0, stream>>>(state, action, cat);
    xsplit<<<(NB * EIN + 255) / 256, blk, 0, stream>>>(cat, EIN, Xh, Xl);
    lif1<5><<<dim3(12, 16), blk, 0, stream>>>(Xh, Xl, W1h, W1l, b1, bitsT_a);
    bitgemm<0><<<dim3(12, NB / 8), blk, 0, stream>>>(bitsT_a, W2h, W2l, b2, nullptr,
                                                     bitsT_b, nullptr, nullptr);
    bitgemm<1><<<dim3(4, NB / 8), blk, 0, stream>>>(bitsT_b, WmlsH, WmlsL, bm, bls,
                                                    nullptr, mean_ws, ls_ws);
    latent_kernel<<<(NB * DIN + 255) / 256, blk, 0, stream>>>(mean_ws, ls_ws, eps, state, out, cat);

    // decoder
    xsplit<<<(NB * DIN + 255) / 256, blk, 0, stream>>>(cat, DIN, Xh, Xl);
    lif1<6><<<dim3(12, 16), blk, 0, stream>>>(Xh, Xl, Wd1h, Wd1l, bd1, bitsT_a);
    bitgemm<0><<<dim3(12, NB / 8), blk, 0, stream>>>(bitsT_a, Wd2h, Wd2l, bd2, nullptr,
                                                     bitsT_b, nullptr, nullptr);
    bitgemm<2><<<dim3(1, NB / 8), blk, 0, stream>>>(bitsT_b, Wu3h, Wu3l, bd3, nullptr,
                                                    nullptr, out, nullptr);
}

// Round 5
// 281.347 us; speedup vs baseline: 28.4609x; 1.3376x over previous
//
#include <hip/hip_runtime.h>
#include <math.h>

#define TT   32
#define NB   2048
#define SDIM 256
#define ADIM 64
#define LDIM 128
#define HID  750
#define KP   768    // padded neuron count (k-dim of layer-2 GEMMs)
#define KW   24     // KP/32 words per batch row (bit layout [b][kw][t])
#define EIN  320    // SDIM + ADIM
#define DIN  384    // SDIM + LDIM
#define NSTEP 12    // KP / 64

typedef float    f32x4 __attribute__((ext_vector_type(4)));
typedef int      i32x4 __attribute__((ext_vector_type(4)));
typedef unsigned u32x4 __attribute__((ext_vector_type(4)));

// v_mfma_f32_16x16x32_bf16: A row=lane&15, k=(lane>>4)*8+e; B col=lane&15;
// C/D col=lane&15, row=(lane>>4)*4+reg.  (verified R2/R3: absmax 0.0)
__device__ __forceinline__ f32x4 mfma16(u32x4 a, u32x4 b, f32x4 c) {
    asm("v_mfma_f32_16x16x32_bf16 %0, %1, %2, %0" : "+v"(c) : "v"(a), "v"(b));
    return c;
}
// v_mfma_i32_16x16x64_i8: A row=lane&15, k=(lane>>4)*16 + reg*4 + byte. (verified R4)
__device__ __forceinline__ i32x4 mfma_i8(u32x4 a, u32x4 b, i32x4 c) {
    asm("v_mfma_i32_16x16x64_i8 %0, %1, %2, %0" : "+v"(c) : "v"(a), "v"(b));
    return c;
}

__device__ __forceinline__ void gload_lds16(void* lds, const void* g) {
    __builtin_amdgcn_global_load_lds(
        (const __attribute__((address_space(1))) unsigned int*)g,
        (__attribute__((address_space(3))) unsigned int*)lds, 16, 0, 0);
}

// ---------------------------------------------------------------------------
// Weight quant to 2-limb i8 (Wq = rint(W*2^19) = hi*256+lo), packed per
// (nb,kstep) 4KB block: off = kg*1024 + (o&63)*16 + (k&15); linear
// global_load_lds copy reproduces the LDS layout the MFMA B-fragment reads.
// ---------------------------------------------------------------------------
__global__ void wsplit_i8(const float* __restrict__ src, int rvalid,
                          char* __restrict__ dh, char* __restrict__ dl,
                          int o_base, int rspan) {
    int i = blockIdx.x * blockDim.x + threadIdx.x;
    if (i >= rspan * KP) return;
    int r = i / KP, k = i % KP;
    float v = (r < rvalid && k < HID) ? src[r * HID + k] : 0.f;
    int q = (int)rintf(v * 524288.f);
    int lo = (q << 24) >> 24;           // sext low byte
    int hi = (q - lo) >> 8;
    int o = o_base + r;
    size_t di = (size_t)((o >> 6) * NSTEP + (k >> 6)) * 4096
              + ((k >> 4) & 3) * 1024 + (o & 63) * 16 + (k & 15);
    dh[di] = (char)hi;
    dl[di] = (char)lo;
}

// ---------------------------------------------------------------------------
// Layer-1 weights: bf16 hi/lo split, packed per (nb,ks) 8KB block:
// elem = (kc*4+kg)*512 + (o&63)*8 + (k&7).
// ---------------------------------------------------------------------------
__global__ void wsplit_bf(const float* __restrict__ src, int K, int KS,
                          unsigned short* __restrict__ dh,
                          unsigned short* __restrict__ dl) {
    int i = blockIdx.x * blockDim.x + threadIdx.x;
    if (i >= KP * K) return;
    int r = i / K, k = i % K;
    float v = (r < HID) ? src[r * K + k] : 0.f;
    unsigned u = __float_as_uint(v);
    unsigned hb = (u + 0x7FFFu + ((u >> 16) & 1u)) >> 16;
    float res = v - __uint_as_float(hb << 16);
    unsigned u2 = __float_as_uint(res);
    unsigned lb = (u2 + 0x7FFFu + ((u2 >> 16) & 1u)) >> 16;
    size_t di = ((size_t)((r >> 6) * KS + (k >> 6)) * 8
               + ((k >> 5) & 1) * 4 + ((k >> 3) & 3)) * 512 + (r & 63) * 8 + (k & 7);
    dh[di] = (unsigned short)hb;
    dl[di] = (unsigned short)lb;
}

// ---------------------------------------------------------------------------
// Activations: bf16 hi/lo split, A-fragment order: idx = ((k>>3)*NB + r)*8 + (k&7)
// ---------------------------------------------------------------------------
__global__ void xsplit(const float* __restrict__ X, int K,
                       unsigned short* __restrict__ dh,
                       unsigned short* __restrict__ dl) {
    int i = blockIdx.x * blockDim.x + threadIdx.x;
    if (i >= NB * K) return;
    int r = i / K, k = i % K;
    float v = X[i];
    unsigned u = __float_as_uint(v);
    unsigned hb = (u + 0x7FFFu + ((u >> 16) & 1u)) >> 16;
    float res = v - __uint_as_float(hb << 16);
    unsigned u2 = __float_as_uint(res);
    unsigned lb = (u2 + 0x7FFFu + ((u2 >> 16) & 1u)) >> 16;
    size_t di = ((size_t)(k >> 3) * NB + r) * 8 + (k & 7);
    dh[di] = (unsigned short)hb;
    dl[di] = (unsigned short)lb;
}

__global__ void concat_enc_kernel(const float* __restrict__ state,
                                  const float* __restrict__ action,
                                  float* __restrict__ cat) {
    int i = blockIdx.x * blockDim.x + threadIdx.x;
    if (i >= NB * EIN) return;
    int b = i / EIN, c = i % EIN;
    cat[i] = (c < SDIM) ? state[b * SDIM + c] : action[b * ADIM + (c - SDIM)];
}

// ---------------------------------------------------------------------------
// Layer-1: bf16 3-product MFMA GEMM (AhBh + AhBl + AlBh) + const-input LIF
// scan + ballot bit-transpose -> bitsT[b][kw][t].
// Block: 4 waves, M=128 batch rows (wave: 32), N=64, K-step 64.
// Double-buffered stage + counted-wait raw barrier (no vmcnt(0)-drain serialization).
// ---------------------------------------------------------------------------
template<int KS>
__global__ __launch_bounds__(256)
void lif1(const unsigned short* __restrict__ Ah,
          const unsigned short* __restrict__ Al,
          const unsigned short* __restrict__ Wh,
          const unsigned short* __restrict__ Wl,
          const float* __restrict__ bias,
          unsigned* __restrict__ obitsT) {
    __shared__ __align__(16) char smraw[32768];  // 2x16KB bufs | epi Sb[128][64] u32
    const int tid = threadIdx.x, wave = tid >> 6, l = tid & 63;
    const int kg = l >> 4, li = l & 15;
    const int nb = blockIdx.x, n0 = nb * 64, mb = blockIdx.y;
    const int r0 = mb * 128 + wave * 32;
    f32x4 acc[2][4] = {};

    auto stage = [&](int buf, int step) {
        const char* sH = (const char*)(Wh + (size_t)(nb * KS + step) * 4096);
        const char* sL = (const char*)(Wl + (size_t)(nb * KS + step) * 4096);
        char* d = smraw + buf * 16384;
#pragma unroll
        for (int j = 0; j < 2; ++j) {
            gload_lds16(d + j * 4096 + tid * 16, sH + j * 4096 + tid * 16);
            gload_lds16(d + 8192 + j * 4096 + tid * 16, sL + j * 4096 + tid * 16);
        }
    };

    stage(0, 0);
    for (int step = 0; step < KS; ++step) {
        asm volatile("s_waitcnt vmcnt(0)" ::: "memory");
        __builtin_amdgcn_s_barrier();
        __builtin_amdgcn_sched_barrier(0);
        // load all A-fragments for this step (issued BEFORE next stage so the
        // compiler's A-wait doesn't drain the staging pipeline)
        u32x4 ah[2][2], al2[2][2];
#pragma unroll
        for (int kc = 0; kc < 2; ++kc)
#pragma unroll
            for (int mt = 0; mt < 2; ++mt) {
                int r = r0 + mt * 16 + li;
                size_t aoff = ((size_t)(step * 8 + kc * 4 + kg) * NB + r) * 8;
                ah[kc][mt]  = *(const u32x4*)(Ah + aoff);
                al2[kc][mt] = *(const u32x4*)(Al + aoff);
            }
        if (step + 1 < KS) stage((step + 1) & 1, step + 1);
        const char* bufB = smraw + (step & 1) * 16384;
        __builtin_amdgcn_s_setprio(1);
#pragma unroll
        for (int kc = 0; kc < 2; ++kc) {
#pragma unroll
            for (int nt = 0; nt < 4; ++nt) {
                int boff = (kc * 4 + kg) * 1024 + (nt * 16 + li) * 16;
                u32x4 bh = *(const u32x4*)(bufB + boff);
                u32x4 bl = *(const u32x4*)(bufB + 8192 + boff);
#pragma unroll
                for (int mt = 0; mt < 2; ++mt) {
                    acc[mt][nt] = mfma16(ah[kc][mt], bh, acc[mt][nt]);
                    acc[mt][nt] = mfma16(ah[kc][mt], bl, acc[mt][nt]);
                    acc[mt][nt] = mfma16(al2[kc][mt], bh, acc[mt][nt]);
                }
            }
        }
        __builtin_amdgcn_s_setprio(0);
    }
    __syncthreads();

    // per-element constant-input LIF scan -> spike word; stash in LDS
    unsigned* Sb = (unsigned*)smraw;  // [128][64]
#pragma unroll
    for (int nt = 0; nt < 4; ++nt) {
        int o = n0 + nt * 16 + li;
        float bo = (o < HID) ? bias[o] : 0.f;
#pragma unroll
        for (int mt = 0; mt < 2; ++mt)
#pragma unroll
            for (int r = 0; r < 4; ++r) {
                float c = acc[mt][nt][r] + bo;
                float v = 0.f;
                unsigned sb = 0u;
#pragma unroll
                for (int t = 0; t < TT; ++t) {
                    float h = 0.5f * (v + c);
                    if (h >= 1.0f) { sb |= (1u << t); v = 0.f; }
                    else           { v = h; }
                }
                Sb[(wave * 32 + mt * 16 + kg * 4 + r) * 64 + nt * 16 + li] = sb;
            }
    }
    __syncthreads();

    // ballot transpose: rows [wave*32, wave*32+32) -> bitsT[b][kw][t]
    for (int rr = 0; rr < 32; ++rr) {
        int row = wave * 32 + rr;
        unsigned wv = Sb[row * 64 + l];
        unsigned myw = 0;
#pragma unroll
        for (int t = 0; t < TT; ++t) {
            unsigned long long m = __ballot((wv >> t) & 1u);
            if ((l & 31) == t) myw = (l < 32) ? (unsigned)m : (unsigned)(m >> 32);
        }
        int b = mb * 128 + row;
        obitsT[((size_t)b * KW + nb * 2 + (l >= 32)) * TT + (l & 31)] = myw;
    }
}

// ---------------------------------------------------------------------------
// i8 MFMA bit-GEMM over transposed spike bits (layout [b][kw][t]).
// Block: 4 waves; tile M=256 (8 b x 32 t; wave: 2 b), N=64, K-step 64.
// Triple-buffered stage, counted s_waitcnt vmcnt(6) + raw s_barrier per step:
// staging + A-prefetch stay in flight across barriers (no drain bubble).
// EPI 0: LIF scan -> ballot transpose -> obitsT
// EPI 1: mean/log_std heads (max over t)   EPI 2: tanh action head
// ---------------------------------------------------------------------------
template<int EPI>
__global__ __launch_bounds__(256)
void bitgemm(const unsigned* __restrict__ bitsT,
             const char* __restrict__ Wh,
             const char* __restrict__ Wl,
             const float* __restrict__ bias,
             const float* __restrict__ bias2,
             unsigned* __restrict__ obitsT,
             float* __restrict__ o0,
             float* __restrict__ o1) {
    __shared__ __align__(16) char smraw[34816];  // 3x8KB bufs | epi [256][34] f32
    const int tid = threadIdx.x;
    const int wave = tid >> 6, l = tid & 63;
    const int kg = l >> 4, li = l & 15;
    const int nb = blockIdx.x, n0 = nb * 64;
    const int by = blockIdx.y;
    const int bb = by * 8 + wave * 2;

    i32x4 acc[4][4][2] = {};

    auto stage = [&](int buf, int step) {
        const char* sH = Wh + (size_t)(nb * NSTEP + step) * 4096;
        const char* sL = Wl + (size_t)(nb * NSTEP + step) * 4096;
        char* d = smraw + buf * 8192;
        gload_lds16(d + tid * 16, sH + tid * 16);
        gload_lds16(d + 4096 + tid * 16, sL + tid * 16);
    };
    // A-word for (mt, step): b = bb + (mt>>1), t = (mt&1)*16 + li
    auto aidx = [&](int mt, int step) -> size_t {
        int b = bb + (mt >> 1);
        int t = (mt & 1) * 16 + li;
        return ((size_t)b * KW + step * 2 + (kg >> 1)) * TT + t;
    };

    stage(0, 0);
    stage(1, 1);
    unsigned aw[4], awn[4];
#pragma unroll
    for (int mt = 0; mt < 4; ++mt) aw[mt] = bitsT[aidx(mt, 0)];

    for (int step = 0; step < NSTEP; ++step) {
        // FIFO: oldest outstanding VMEM = stage(step) [2 ops]; <=8 outstanding
        // total, so vmcnt(6) guarantees current buffer complete pre-barrier.
        asm volatile("s_waitcnt vmcnt(6)" ::: "memory");
        __builtin_amdgcn_s_barrier();
        __builtin_amdgcn_sched_barrier(0);
        if (step + 2 < NSTEP) stage((step + 2) % 3, step + 2);
        if (step + 1 < NSTEP) {
#pragma unroll
            for (int mt = 0; mt < 4; ++mt) awn[mt] = bitsT[aidx(mt, step + 1)];
        }
        const char* bufB = smraw + (step % 3) * 8192;
        const unsigned fld = (kg & 1) * 16;
        u32x4 afrag[4];
#pragma unroll
        for (int mt = 0; mt < 4; ++mt) {
            unsigned w = aw[mt] >> fld;
            u32x4 a;
#pragma unroll
            for (int j = 0; j < 4; ++j) {
                unsigned x = (w >> (4 * j)) & 0xFu;
                a[j] = (x * 0x00204081u) & 0x01010101u;
            }
            afrag[mt] = a;
        }
        __builtin_amdgcn_s_setprio(1);
#pragma unroll
        for (int nt = 0; nt < 4; ++nt) {
            int boff = kg * 1024 + (nt * 16 + li) * 16;
            u32x4 bh = *(const u32x4*)(bufB + boff);
            u32x4 bl = *(const u32x4*)(bufB + 4096 + boff);
#pragma unroll
            for (int mt = 0; mt < 4; ++mt) {
                acc[mt][nt][0] = mfma_i8(afrag[mt], bh, acc[mt][nt][0]);
                acc[mt][nt][1] = mfma_i8(afrag[mt], bl, acc[mt][nt][1]);
            }
        }
        __builtin_amdgcn_s_setprio(0);
#pragma unroll
        for (int mt = 0; mt < 4; ++mt) aw[mt] = awn[mt];
    }
    __syncthreads();

    // epilogue: combine limbs, 2 passes of 32 cols through LDS [256][34]
    float* Sf = (float*)smraw;
#pragma unroll
    for (int p = 0; p < 2; ++p) {
#pragma unroll
        for (int mt = 0; mt < 4; ++mt)
#pragma unroll
            for (int ntl = 0; ntl < 2; ++ntl) {
                int nt = p * 2 + ntl;
#pragma unroll
                for (int r = 0; r < 4; ++r) {
                    int cmb = (acc[mt][nt][0][r] << 8) + acc[mt][nt][1][r];
                    Sf[(wave * 64 + mt * 16 + kg * 4 + r) * 34 + ntl * 16 + li]
                        = (float)cmb * (1.f / 524288.f);
                }
            }
        __syncthreads();

        int lb = tid >> 5, col = tid & 31;
        int o = n0 + p * 32 + col;
        int b = by * 8 + lb;
        if (EPI == 0) {
            float bo = (o < HID) ? bias[o] : 0.f;
            float v = 0.f;
            unsigned sb = 0u;
#pragma unroll
            for (int t = 0; t < TT; ++t) {
                float h = 0.5f * (v + Sf[(lb * 32 + t) * 34 + col] + bo);
                if (h >= 1.0f) { sb |= (1u << t); v = 0.f; }
                else           { v = h; }
            }
            if (o >= HID) sb = 0u;
            // ballot transpose within wave (lanes 0..31: b_even, 32..63: b_odd)
            unsigned myw = 0;
#pragma unroll
            for (int t = 0; t < TT; ++t) {
                unsigned long long m = __ballot((sb >> t) & 1u);
                if ((l & 31) == t) myw = (l < 32) ? (unsigned)m : (unsigned)(m >> 32);
            }
            int bw = by * 8 + wave * 2 + (l >= 32);
            obitsT[((size_t)bw * KW + nb * 2 + p) * TT + (l & 31)] = myw;
        } else {
            float mx = -1e30f;
#pragma unroll
            for (int t = 0; t < TT; ++t)
                mx = fmaxf(mx, Sf[(lb * 32 + t) * 34 + col]);
            if (EPI == 1) {
                float bo = (o < LDIM) ? bias[o] : bias2[o - LDIM];
                float val = 0.5f * (mx + bo);
                if (o < LDIM) o0[(size_t)b * LDIM + o] = val;
                else          o1[(size_t)b * LDIM + (o - LDIM)] = val;
            } else {
                o0[(size_t)b * ADIM + o] = tanhf(0.5f * (mx + bias[o]));
            }
        }
        __syncthreads();
    }
}

// ---------------------------------------------------------------------------
__global__ void latent_kernel(const float* __restrict__ mean_ws,
                              const float* __restrict__ ls_ws,
                              const float* __restrict__ eps,
                              const float* __restrict__ state,
                              float* __restrict__ out,
                              float* __restrict__ cat_d) {
    int i = blockIdx.x * blockDim.x + threadIdx.x;
    if (i >= NB * DIN) return;
    int b = i / DIN, c = i % DIN;
    if (c < SDIM) {
        cat_d[i] = state[b * SDIM + c];
    } else {
        int o = c - SDIM;
        float m = mean_ws[b * LDIM + o];
        float l = ls_ws[b * LDIM + o];
        l = fminf(fmaxf(l, -4.0f), 15.0f);
        float s = expf(l);
        cat_d[i] = m + s * eps[b * LDIM + o];
        out[NB * ADIM + b * LDIM + o] = m;
        out[NB * ADIM + NB * LDIM + b * LDIM + o] = s;
    }
}

// ---------------------------------------------------------------------------
extern "C" void kernel_launch(void* const* d_in, const int* in_sizes, int n_in,
                              void* d_out, int out_size, void* d_ws, size_t ws_size,
                              hipStream_t stream) {
    const float* state  = (const float*)d_in[0];
    const float* action = (const float*)d_in[1];
    const float* eps    = (const float*)d_in[2];
    const float* W1  = (const float*)d_in[3];
    const float* b1  = (const float*)d_in[4];
    const float* W2  = (const float*)d_in[5];
    const float* b2  = (const float*)d_in[6];
    const float* Wm  = (const float*)d_in[7];
    const float* bm  = (const float*)d_in[8];
    const float* Wls = (const float*)d_in[9];
    const float* bls = (const float*)d_in[10];
    const float* Wd1 = (const float*)d_in[11];
    const float* bd1 = (const float*)d_in[12];
    const float* Wd2 = (const float*)d_in[13];
    const float* bd2 = (const float*)d_in[14];
    const float* Wd3 = (const float*)d_in[15];
    const float* bd3 = (const float*)d_in[16];
    float* out = (float*)d_out;

    char* ws = (char*)d_ws;
    size_t off = 0;
    auto alloc = [&](size_t bytes) {
        void* p = ws + off;
        off += (bytes + 255) & ~(size_t)255;
        return p;
    };
    unsigned*       bitsT_a = (unsigned*)alloc((size_t)NB * TT * KW * 4);
    unsigned*       bitsT_b = (unsigned*)alloc((size_t)NB * TT * KW * 4);
    float*          cat     = (float*)   alloc((size_t)NB * DIN * 4);
    float*          mean_ws = (float*)   alloc((size_t)NB * LDIM * 4);
    float*          ls_ws   = (float*)   alloc((size_t)NB * LDIM * 4);
    unsigned short* Xh      = (unsigned short*)alloc((size_t)NB * DIN * 2);
    unsigned short* Xl      = (unsigned short*)alloc((size_t)NB * DIN * 2);
    char*           W2h     = (char*)alloc((size_t)KP * KP);
    char*           W2l     = (char*)alloc((size_t)KP * KP);
    char*           Wd2h    = (char*)alloc((size_t)KP * KP);
    char*           Wd2l    = (char*)alloc((size_t)KP * KP);
    char*           WmlsH   = (char*)alloc((size_t)256 * KP);
    char*           WmlsL   = (char*)alloc((size_t)256 * KP);
    char*           Wu3h    = (char*)alloc((size_t)64 * KP);
    char*           Wu3l    = (char*)alloc((size_t)64 * KP);
    unsigned short* W1h     = (unsigned short*)alloc((size_t)KP * EIN * 2);
    unsigned short* W1l     = (unsigned short*)alloc((size_t)KP * EIN * 2);
    unsigned short* Wd1h    = (unsigned short*)alloc((size_t)KP * DIN * 2);
    unsigned short* Wd1l    = (unsigned short*)alloc((size_t)KP * DIN * 2);

    dim3 blk(256);

    // weight prep
    wsplit_i8<<<(KP * KP + 255) / 256, blk, 0, stream>>>(W2,  HID,  W2h,  W2l,  0,   KP);
    wsplit_i8<<<(KP * KP + 255) / 256, blk, 0, stream>>>(Wd2, HID,  Wd2h, Wd2l, 0,   KP);
    wsplit_i8<<<(128 * KP + 255) / 256, blk, 0, stream>>>(Wm,  LDIM, WmlsH, WmlsL, 0,   128);
    wsplit_i8<<<(128 * KP + 255) / 256, blk, 0, stream>>>(Wls, LDIM, WmlsH, WmlsL, 128, 128);
    wsplit_i8<<<(64 * KP + 255) / 256, blk, 0, stream>>>(Wd3, ADIM, Wu3h, Wu3l, 0, 64);
    wsplit_bf<<<(KP * EIN + 255) / 256, blk, 0, stream>>>(W1,  EIN, 5, W1h,  W1l);
    wsplit_bf<<<(KP * DIN + 255) / 256, blk, 0, stream>>>(Wd1, DIN, 6, Wd1h, Wd1l);

    // encoder
    concat_enc_kernel<<<(NB * EIN + 255) / 256, blk, 0, stream>>>(state, action, cat);
    xsplit<<<(NB * EIN + 255) / 256, blk, 0, stream>>>(cat, EIN, Xh, Xl);
    lif1<5><<<dim3(12, 16), blk, 0, stream>>>(Xh, Xl, W1h, W1l, b1, bitsT_a);
    bitgemm<0><<<dim3(12, NB / 8), blk, 0, stream>>>(bitsT_a, W2h, W2l, b2, nullptr,
                                                     bitsT_b, nullptr, nullptr);
    bitgemm<1><<<dim3(4, NB / 8), blk, 0, stream>>>(bitsT_b, WmlsH, WmlsL, bm, bls,
                                                    nullptr, mean_ws, ls_ws);
    latent_kernel<<<(NB * DIN + 255) / 256, blk, 0, stream>>>(mean_ws, ls_ws, eps, state, out, cat);

    // decoder
    xsplit<<<(NB * DIN + 255) / 256, blk, 0, stream>>>(cat, DIN, Xh, Xl);
    lif1<6><<<dim3(12, 16), blk, 0, stream>>>(Xh, Xl, Wd1h, Wd1l, bd1, bitsT_a);
    bitgemm<0><<<dim3(12, NB / 8), blk, 0, stream>>>(bitsT_a, Wd2h, Wd2l, bd2, nullptr,
                                                     bitsT_b, nullptr, nullptr);
    bitgemm<2><<<dim3(1, NB / 8), blk, 0, stream>>>(bitsT_b, Wu3h, Wu3l, bd3, nullptr,
                                                    nullptr, out, nullptr);
}

// Round 7
// 263.539 us; speedup vs baseline: 30.3840x; 1.0676x over previous
//
#include <hip/hip_runtime.h>
#include <math.h>

#define TT   32
#define NB   2048
#define SDIM 256
#define ADIM 64
#define LDIM 128
#define HID  750
#define KP   768    // padded neuron count (k-dim of layer-2 GEMMs)
#define KW   24     // KP/32 words per batch row (bit layout [b][kw][t])
#define EIN  320    // SDIM + ADIM
#define DIN  384    // SDIM + LDIM
#define NSTEP 12    // KP / 64

typedef float    f32x4 __attribute__((ext_vector_type(4)));
typedef int      i32x4 __attribute__((ext_vector_type(4)));
typedef unsigned u32x4 __attribute__((ext_vector_type(4)));

// v_mfma_f32_16x16x32_bf16: A row=lane&15, k=(lane>>4)*8+e; B col=lane&15;
// C/D col=lane&15, row=(lane>>4)*4+reg.  (verified R2/R3: absmax 0.0)
__device__ __forceinline__ f32x4 mfma16(u32x4 a, u32x4 b, f32x4 c) {
    asm("v_mfma_f32_16x16x32_bf16 %0, %1, %2, %0" : "+v"(c) : "v"(a), "v"(b));
    return c;
}
// v_mfma_i32_16x16x64_i8: A row=lane&15, k=(lane>>4)*16 + reg*4 + byte. (verified R4/R5)
__device__ __forceinline__ i32x4 mfma_i8(u32x4 a, u32x4 b, i32x4 c) {
    asm("v_mfma_i32_16x16x64_i8 %0, %1, %2, %0" : "+v"(c) : "v"(a), "v"(b));
    return c;
}

__device__ __forceinline__ void gload_lds16(void* lds, const void* g) {
    __builtin_amdgcn_global_load_lds(
        (const __attribute__((address_space(1))) unsigned int*)g,
        (__attribute__((address_space(3))) unsigned int*)lds, 16, 0, 0);
}

// round-to-nearest-even bf16 hi/lo split (verified R2..R5)
__device__ __forceinline__ void bfsplit(float v, unsigned& hb, unsigned& lb) {
    unsigned u = __float_as_uint(v);
    hb = (u + 0x7FFFu + ((u >> 16) & 1u)) >> 16;
    float res = v - __uint_as_float(hb << 16);
    unsigned u2 = __float_as_uint(res);
    lb = (u2 + 0x7FFFu + ((u2 >> 16) & 1u)) >> 16;
}

// ---------------------------------------------------------------------------
// Merged weight-quant kernel: all five i8 2-limb splits in one launch.
// Layout per (o_blk,k_blk) 4KB block: off = kg*1024 + (o&63)*16 + (k&15).
// ---------------------------------------------------------------------------
#define I8_E1 589824          // W2   (768 rows)
#define I8_E2 1179648         // Wd2  (768 rows)
#define I8_E3 1277952         // Wm   (128 rows)
#define I8_E4 1376256         // Wls  (128 rows)
#define I8_E5 1425408         // Wd3  (64 rows)
__global__ void wsplit_i8_all(const float* __restrict__ W2,
                              const float* __restrict__ Wd2,
                              const float* __restrict__ Wm,
                              const float* __restrict__ Wls,
                              const float* __restrict__ Wd3,
                              char* __restrict__ W2h,  char* __restrict__ W2l,
                              char* __restrict__ Wd2h, char* __restrict__ Wd2l,
                              char* __restrict__ WmlsH, char* __restrict__ WmlsL,
                              char* __restrict__ Wu3h, char* __restrict__ Wu3l) {
    int i = blockIdx.x * blockDim.x + threadIdx.x;
    if (i >= I8_E5) return;
    const float* src; char* dh; char* dl; int rvalid, o_base;
    if (i < I8_E1)      { src = W2;  dh = W2h;  dl = W2l;  rvalid = HID;  o_base = 0; }
    else if (i < I8_E2) { i -= I8_E1; src = Wd2; dh = Wd2h; dl = Wd2l; rvalid = HID;  o_base = 0; }
    else if (i < I8_E3) { i -= I8_E2; src = Wm;  dh = WmlsH; dl = WmlsL; rvalid = LDIM; o_base = 0; }
    else if (i < I8_E4) { i -= I8_E3; src = Wls; dh = WmlsH; dl = WmlsL; rvalid = LDIM; o_base = 128; }
    else                { i -= I8_E4; src = Wd3; dh = Wu3h; dl = Wu3l; rvalid = ADIM; o_base = 0; }
    int r = i / KP, k = i % KP;
    float v = (r < rvalid && k < HID) ? src[r * HID + k] : 0.f;
    int q = (int)rintf(v * 524288.f);
    int lo = (q << 24) >> 24;           // sext low byte
    int hi = (q - lo) >> 8;
    int o = o_base + r;
    size_t di = (size_t)((o >> 6) * NSTEP + (k >> 6)) * 4096
              + ((k >> 4) & 3) * 1024 + (o & 63) * 16 + (k & 15);
    dh[di] = (char)hi;
    dl[di] = (char)lo;
}

// ---------------------------------------------------------------------------
// Merged layer-1 weight split (W1 KS=5, Wd1 KS=6), bf16 hi/lo packed per
// (nb,ks64) 8KB block: elem = (kc*4+kg)*512 + (o&63)*8 + (k&7).
// ---------------------------------------------------------------------------
#define BF_E1 245760          // W1 (KP x EIN)
#define BF_E2 540672          // Wd1 (KP x DIN)
__global__ void wsplit_bf_all(const float* __restrict__ W1,
                              const float* __restrict__ Wd1,
                              unsigned short* __restrict__ W1h,
                              unsigned short* __restrict__ W1l,
                              unsigned short* __restrict__ Wd1h,
                              unsigned short* __restrict__ Wd1l) {
    int i = blockIdx.x * blockDim.x + threadIdx.x;
    if (i >= BF_E2) return;
    const float* src; unsigned short* dh; unsigned short* dl; int K, KS;
    if (i < BF_E1) { src = W1; dh = W1h; dl = W1l; K = EIN; KS = 5; }
    else { i -= BF_E1; src = Wd1; dh = Wd1h; dl = Wd1l; K = DIN; KS = 6; }
    int r = i / K, k = i % K;
    float v = (r < HID) ? src[r * K + k] : 0.f;
    unsigned hb, lb;
    bfsplit(v, hb, lb);
    size_t di = ((size_t)((r >> 6) * KS + (k >> 6)) * 8
               + ((k >> 5) & 1) * 4 + ((k >> 3) & 3)) * 512 + (r & 63) * 8 + (k & 7);
    dh[di] = (unsigned short)hb;
    dl[di] = (unsigned short)lb;
}

// ---------------------------------------------------------------------------
// Fused encoder concat + bf16 hi/lo split, k-chunk-major A layout:
// Xh/Xl idx = ((k>>3)*NB + b)*8 + (k&7). Thread t = c8*NB + b (b fastest ->
// 16B/lane coalesced writes).
// ---------------------------------------------------------------------------
__global__ void concat_xsplit_enc(const float* __restrict__ state,
                                  const float* __restrict__ action,
                                  unsigned short* __restrict__ Xh,
                                  unsigned short* __restrict__ Xl) {
    int t = blockIdx.x * blockDim.x + threadIdx.x;
    if (t >= NB * (EIN / 8)) return;
    int b = t & (NB - 1), c8 = t >> 11;
    float vals[8];
    if (c8 < SDIM / 8) {
        const float* src = state + (size_t)b * SDIM + c8 * 8;
#pragma unroll
        for (int j = 0; j < 8; ++j) vals[j] = src[j];
    } else {
        const float* src = action + (size_t)b * ADIM + (c8 * 8 - SDIM);
#pragma unroll
        for (int j = 0; j < 8; ++j) vals[j] = src[j];
    }
    unsigned hs[8], ls[8];
#pragma unroll
    for (int j = 0; j < 8; ++j) bfsplit(vals[j], hs[j], ls[j]);
    u32x4 ph, pl;
#pragma unroll
    for (int j = 0; j < 4; ++j) {
        ph[j] = hs[2 * j] | (hs[2 * j + 1] << 16);
        pl[j] = ls[2 * j] | (ls[2 * j + 1] << 16);
    }
    *(u32x4*)(Xh + (size_t)t * 8) = ph;
    *(u32x4*)(Xl + (size_t)t * 8) = pl;
}

// ---------------------------------------------------------------------------
// Fused latent + decoder concat + split: std=exp(clip(ls)), zlat=mean+std*eps,
// writes mean/std to d_out and [state,zlat] hi/lo directly into Xh/Xl.
// ---------------------------------------------------------------------------
__global__ void latent_xsplit(const float* __restrict__ mean_ws,
                              const float* __restrict__ ls_ws,
                              const float* __restrict__ eps,
                              const float* __restrict__ state,
                              float* __restrict__ out,
                              unsigned short* __restrict__ Xh,
                              unsigned short* __restrict__ Xl) {
    int t = blockIdx.x * blockDim.x + threadIdx.x;
    if (t >= NB * (DIN / 8)) return;
    int b = t & (NB - 1), c8 = t >> 11;
    float vals[8];
    if (c8 < SDIM / 8) {
        const float* src = state + (size_t)b * SDIM + c8 * 8;
#pragma unroll
        for (int j = 0; j < 8; ++j) vals[j] = src[j];
    } else {
        int o0 = c8 * 8 - SDIM;
#pragma unroll
        for (int j = 0; j < 8; ++j) {
            int o = o0 + j;
            float m = mean_ws[(size_t)b * LDIM + o];
            float l = ls_ws[(size_t)b * LDIM + o];
            l = fminf(fmaxf(l, -4.0f), 15.0f);
            float s = expf(l);
            vals[j] = m + s * eps[(size_t)b * LDIM + o];
            out[NB * ADIM + (size_t)b * LDIM + o] = m;
            out[NB * ADIM + NB * LDIM + (size_t)b * LDIM + o] = s;
        }
    }
    unsigned hs[8], ls[8];
#pragma unroll
    for (int j = 0; j < 8; ++j) bfsplit(vals[j], hs[j], ls[j]);
    u32x4 ph, pl;
#pragma unroll
    for (int j = 0; j < 4; ++j) {
        ph[j] = hs[2 * j] | (hs[2 * j + 1] << 16);
        pl[j] = ls[2 * j] | (ls[2 * j + 1] << 16);
    }
    *(u32x4*)(Xh + (size_t)t * 8) = ph;
    *(u32x4*)(Xl + (size_t)t * 8) = pl;
}

// ---------------------------------------------------------------------------
// Layer-1: bf16 3-product MFMA GEMM (AhBh + AhBl + AlBh) + const-input LIF
// scan + ballot bit-transpose -> bitsT[b][kw][t].   (R5-verified structure)
// Block: 4 waves, M=128 rows (wave: 32), N=64, K-step 64.
// ---------------------------------------------------------------------------
template<int KS>
__global__ __launch_bounds__(256)
void lif1(const unsigned short* __restrict__ Ah,
          const unsigned short* __restrict__ Al,
          const unsigned short* __restrict__ Wh,
          const unsigned short* __restrict__ Wl,
          const float* __restrict__ bias,
          unsigned* __restrict__ obitsT) {
    __shared__ __align__(16) char smraw[32768];  // 2x16KB bufs | epi Sb[128][64] u32
    const int tid = threadIdx.x, wave = tid >> 6, l = tid & 63;
    const int kg = l >> 4, li = l & 15;
    const int nb = blockIdx.x, n0 = nb * 64, mb = blockIdx.y;
    const int r0 = mb * 128 + wave * 32;
    f32x4 acc[2][4] = {};

    auto stage = [&](int buf, int step) {
        const char* sH = (const char*)(Wh + (size_t)(nb * KS + step) * 4096);
        const char* sL = (const char*)(Wl + (size_t)(nb * KS + step) * 4096);
        char* d = smraw + buf * 16384;
#pragma unroll
        for (int j = 0; j < 2; ++j) {
            gload_lds16(d + j * 4096 + tid * 16, sH + j * 4096 + tid * 16);
            gload_lds16(d + 8192 + j * 4096 + tid * 16, sL + j * 4096 + tid * 16);
        }
    };

    stage(0, 0);
    for (int step = 0; step < KS; ++step) {
        asm volatile("s_waitcnt vmcnt(0)" ::: "memory");
        __builtin_amdgcn_s_barrier();
        __builtin_amdgcn_sched_barrier(0);
        u32x4 ah[2][2], al2[2][2];
#pragma unroll
        for (int kc = 0; kc < 2; ++kc)
#pragma unroll
            for (int mt = 0; mt < 2; ++mt) {
                int r = r0 + mt * 16 + li;
                size_t aoff = ((size_t)(step * 8 + kc * 4 + kg) * NB + r) * 8;
                ah[kc][mt]  = *(const u32x4*)(Ah + aoff);
                al2[kc][mt] = *(const u32x4*)(Al + aoff);
            }
        if (step + 1 < KS) stage((step + 1) & 1, step + 1);
        const char* bufB = smraw + (step & 1) * 16384;
        __builtin_amdgcn_s_setprio(1);
#pragma unroll
        for (int kc = 0; kc < 2; ++kc) {
#pragma unroll
            for (int nt = 0; nt < 4; ++nt) {
                int boff = (kc * 4 + kg) * 1024 + (nt * 16 + li) * 16;
                u32x4 bh = *(const u32x4*)(bufB + boff);
                u32x4 bl = *(const u32x4*)(bufB + 8192 + boff);
#pragma unroll
                for (int mt = 0; mt < 2; ++mt) {
                    acc[mt][nt] = mfma16(ah[kc][mt], bh, acc[mt][nt]);
                    acc[mt][nt] = mfma16(ah[kc][mt], bl, acc[mt][nt]);
                    acc[mt][nt] = mfma16(al2[kc][mt], bh, acc[mt][nt]);
                }
            }
        }
        __builtin_amdgcn_s_setprio(0);
    }
    __syncthreads();

    unsigned* Sb = (unsigned*)smraw;  // [128][64]
#pragma unroll
    for (int nt = 0; nt < 4; ++nt) {
        int o = n0 + nt * 16 + li;
        float bo = (o < HID) ? bias[o] : 0.f;
#pragma unroll
        for (int mt = 0; mt < 2; ++mt)
#pragma unroll
            for (int r = 0; r < 4; ++r) {
                float c = acc[mt][nt][r] + bo;
                float v = 0.f;
                unsigned sb = 0u;
#pragma unroll
                for (int t = 0; t < TT; ++t) {
                    float h = 0.5f * (v + c);
                    if (h >= 1.0f) { sb |= (1u << t); v = 0.f; }
                    else           { v = h; }
                }
                Sb[(wave * 32 + mt * 16 + kg * 4 + r) * 64 + nt * 16 + li] = sb;
            }
    }
    __syncthreads();

    for (int rr = 0; rr < 32; ++rr) {
        int row = wave * 32 + rr;
        unsigned wv = Sb[row * 64 + l];
        unsigned myw = 0;
#pragma unroll
        for (int t = 0; t < TT; ++t) {
            unsigned long long m = __ballot((wv >> t) & 1u);
            if ((l & 31) == t) myw = (l < 32) ? (unsigned)m : (unsigned)(m >> 32);
        }
        int b = mb * 128 + row;
        obitsT[((size_t)b * KW + nb * 2 + (l >= 32)) * TT + (l & 31)] = myw;
    }
}

// ---------------------------------------------------------------------------
// i8 MFMA bit-GEMM over transposed spike bits (layout [b][kw][t]).
// R5-verified: triple-buffered stage, counted s_waitcnt vmcnt(6) + raw
// s_barrier per step. Block: 4 waves; M=256 (8 b x 32 t), N=64, K-step 64.
// EPI 0: LIF -> ballot transpose; EPI 1: mean/log_std; EPI 2: tanh head.
// ---------------------------------------------------------------------------
template<int EPI>
__global__ __launch_bounds__(256)
void bitgemm(const unsigned* __restrict__ bitsT,
             const char* __restrict__ Wh,
             const char* __restrict__ Wl,
             const float* __restrict__ bias,
             const float* __restrict__ bias2,
             unsigned* __restrict__ obitsT,
             float* __restrict__ o0,
             float* __restrict__ o1) {
    __shared__ __align__(16) char smraw[34816];  // 3x8KB bufs | epi [256][34] f32
    const int tid = threadIdx.x;
    const int wave = tid >> 6, l = tid & 63;
    const int kg = l >> 4, li = l & 15;
    const int nb = blockIdx.x, n0 = nb * 64;
    const int by = blockIdx.y;
    const int bb = by * 8 + wave * 2;

    i32x4 acc[4][4][2] = {};

    auto stage = [&](int buf, int step) {
        const char* sH = Wh + (size_t)(nb * NSTEP + step) * 4096;
        const char* sL = Wl + (size_t)(nb * NSTEP + step) * 4096;
        char* d = smraw + buf * 8192;
        gload_lds16(d + tid * 16, sH + tid * 16);
        gload_lds16(d + 4096 + tid * 16, sL + tid * 16);
    };
    auto aidx = [&](int mt, int step) -> size_t {
        int b = bb + (mt >> 1);
        int t = (mt & 1) * 16 + li;
        return ((size_t)b * KW + step * 2 + (kg >> 1)) * TT + t;
    };

    stage(0, 0);
    stage(1, 1);
    unsigned aw[4], awn[4];
#pragma unroll
    for (int mt = 0; mt < 4; ++mt) aw[mt] = bitsT[aidx(mt, 0)];

    for (int step = 0; step < NSTEP; ++step) {
        asm volatile("s_waitcnt vmcnt(6)" ::: "memory");
        __builtin_amdgcn_s_barrier();
        __builtin_amdgcn_sched_barrier(0);
        if (step + 2 < NSTEP) stage((step + 2) % 3, step + 2);
        if (step + 1 < NSTEP) {
#pragma unroll
            for (int mt = 0; mt < 4; ++mt) awn[mt] = bitsT[aidx(mt, step + 1)];
        }
        const char* bufB = smraw + (step % 3) * 8192;
        const unsigned fld = (kg & 1) * 16;
        u32x4 afrag[4];
#pragma unroll
        for (int mt = 0; mt < 4; ++mt) {
            unsigned w = aw[mt] >> fld;
            u32x4 a;
#pragma unroll
            for (int j = 0; j < 4; ++j)
                a[j] = __umul24((w >> (4 * j)) & 0xFu, 0x00204081u) & 0x01010101u;
            afrag[mt] = a;
        }
        __builtin_amdgcn_s_setprio(1);
#pragma unroll
        for (int nt = 0; nt < 4; ++nt) {
            int boff = kg * 1024 + (nt * 16 + li) * 16;
            u32x4 bh = *(const u32x4*)(bufB + boff);
            u32x4 bl = *(const u32x4*)(bufB + 4096 + boff);
#pragma unroll
            for (int mt = 0; mt < 4; ++mt) {
                acc[mt][nt][0] = mfma_i8(afrag[mt], bh, acc[mt][nt][0]);
                acc[mt][nt][1] = mfma_i8(afrag[mt], bl, acc[mt][nt][1]);
            }
        }
        __builtin_amdgcn_s_setprio(0);
#pragma unroll
        for (int mt = 0; mt < 4; ++mt) aw[mt] = awn[mt];
    }
    __syncthreads();

    float* Sf = (float*)smraw;
#pragma unroll
    for (int p = 0; p < 2; ++p) {
#pragma unroll
        for (int mt = 0; mt < 4; ++mt)
#pragma unroll
            for (int ntl = 0; ntl < 2; ++ntl) {
                int nt = p * 2 + ntl;
#pragma unroll
                for (int r = 0; r < 4; ++r) {
                    int cmb = (acc[mt][nt][0][r] << 8) + acc[mt][nt][1][r];
                    Sf[(wave * 64 + mt * 16 + kg * 4 + r) * 34 + ntl * 16 + li]
                        = (float)cmb * (1.f / 524288.f);
                }
            }
        __syncthreads();

        int lb = tid >> 5, col = tid & 31;
        int o = n0 + p * 32 + col;
        int b = by * 8 + lb;
        if (EPI == 0) {
            float bo = (o < HID) ? bias[o] : 0.f;
            float v = 0.f;
            unsigned sb = 0u;
#pragma unroll
            for (int t = 0; t < TT; ++t) {
                float h = 0.5f * (v + Sf[(lb * 32 + t) * 34 + col] + bo);
                if (h >= 1.0f) { sb |= (1u << t); v = 0.f; }
                else           { v = h; }
            }
            if (o >= HID) sb = 0u;
            unsigned myw = 0;
#pragma unroll
            for (int t = 0; t < TT; ++t) {
                unsigned long long m = __ballot((sb >> t) & 1u);
                if ((l & 31) == t) myw = (l < 32) ? (unsigned)m : (unsigned)(m >> 32);
            }
            int bw = by * 8 + wave * 2 + (l >= 32);
            obitsT[((size_t)bw * KW + nb * 2 + p) * TT + (l & 31)] = myw;
        } else {
            float mx = -1e30f;
#pragma unroll
            for (int t = 0; t < TT; ++t)
                mx = fmaxf(mx, Sf[(lb * 32 + t) * 34 + col]);
            if (EPI == 1) {
                float bo = (o < LDIM) ? bias[o] : bias2[o - LDIM];
                float val = 0.5f * (mx + bo);
                if (o < LDIM) o0[(size_t)b * LDIM + o] = val;
                else          o1[(size_t)b * LDIM + (o - LDIM)] = val;
            } else {
                o0[(size_t)b * ADIM + o] = tanhf(0.5f * (mx + bias[o]));
            }
        }
        __syncthreads();
    }
}

// ---------------------------------------------------------------------------
extern "C" void kernel_launch(void* const* d_in, const int* in_sizes, int n_in,
                              void* d_out, int out_size, void* d_ws, size_t ws_size,
                              hipStream_t stream) {
    const float* state  = (const float*)d_in[0];
    const float* action = (const float*)d_in[1];
    const float* eps    = (const float*)d_in[2];
    const float* W1  = (const float*)d_in[3];
    const float* b1  = (const float*)d_in[4];
    const float* W2  = (const float*)d_in[5];
    const float* b2  = (const float*)d_in[6];
    const float* Wm  = (const float*)d_in[7];
    const float* bm  = (const float*)d_in[8];
    const float* Wls = (const float*)d_in[9];
    const float* bls = (const float*)d_in[10];
    const float* Wd1 = (const float*)d_in[11];
    const float* bd1 = (const float*)d_in[12];
    const float* Wd2 = (const float*)d_in[13];
    const float* bd2 = (const float*)d_in[14];
    const float* Wd3 = (const float*)d_in[15];
    const float* bd3 = (const float*)d_in[16];
    float* out = (float*)d_out;

    char* ws = (char*)d_ws;
    size_t off = 0;
    auto alloc = [&](size_t bytes) {
        void* p = ws + off;
        off += (bytes + 255) & ~(size_t)255;
        return p;
    };
    unsigned*       bitsT_a = (unsigned*)alloc((size_t)NB * TT * KW * 4);
    unsigned*       bitsT_b = (unsigned*)alloc((size_t)NB * TT * KW * 4);
    float*          mean_ws = (float*)   alloc((size_t)NB * LDIM * 4);
    float*          ls_ws   = (float*)   alloc((size_t)NB * LDIM * 4);
    unsigned short* Xh      = (unsigned short*)alloc((size_t)NB * DIN * 2);
    unsigned short* Xl      = (unsigned short*)alloc((size_t)NB * DIN * 2);
    char*           W2h     = (char*)alloc((size_t)KP * KP);
    char*           W2l     = (char*)alloc((size_t)KP * KP);
    char*           Wd2h    = (char*)alloc((size_t)KP * KP);
    char*           Wd2l    = (char*)alloc((size_t)KP * KP);
    char*           WmlsH   = (char*)alloc((size_t)256 * KP);
    char*           WmlsL   = (char*)alloc((size_t)256 * KP);
    char*           Wu3h    = (char*)alloc((size_t)64 * KP);
    char*           Wu3l    = (char*)alloc((size_t)64 * KP);
    unsigned short* W1h     = (unsigned short*)alloc((size_t)KP * EIN * 2);
    unsigned short* W1l     = (unsigned short*)alloc((size_t)KP * EIN * 2);
    unsigned short* Wd1h    = (unsigned short*)alloc((size_t)KP * DIN * 2);
    unsigned short* Wd1l    = (unsigned short*)alloc((size_t)KP * DIN * 2);

    dim3 blk(256);

    // weight prep (2 launches)
    wsplit_i8_all<<<(I8_E5 + 255) / 256, blk, 0, stream>>>(
        W2, Wd2, Wm, Wls, Wd3, W2h, W2l, Wd2h, Wd2l, WmlsH, WmlsL, Wu3h, Wu3l);
    wsplit_bf_all<<<(BF_E2 + 255) / 256, blk, 0, stream>>>(
        W1, Wd1, W1h, W1l, Wd1h, Wd1l);

    // encoder
    concat_xsplit_enc<<<(NB * (EIN / 8) + 255) / 256, blk, 0, stream>>>(state, action, Xh, Xl);
    lif1<5><<<dim3(12, 16), blk, 0, stream>>>(Xh, Xl, W1h, W1l, b1, bitsT_a);
    bitgemm<0><<<dim3(12, NB / 8), blk, 0, stream>>>(bitsT_a, W2h, W2l, b2, nullptr,
                                                     bitsT_b, nullptr, nullptr);
    bitgemm<1><<<dim3(4, NB / 8), blk, 0, stream>>>(bitsT_b, WmlsH, WmlsL, bm, bls,
                                                    nullptr, mean_ws, ls_ws);
    latent_xsplit<<<(NB * (DIN / 8) + 255) / 256, blk, 0, stream>>>(
        mean_ws, ls_ws, eps, state, out, Xh, Xl);

    // decoder
    lif1<6><<<dim3(12, 16), blk, 0, stream>>>(Xh, Xl, Wd1h, Wd1l, bd1, bitsT_a);
    bitgemm<0><<<dim3(12, NB / 8), blk, 0, stream>>>(bitsT_a, Wd2h, Wd2l, bd2, nullptr,
                                                     bitsT_b, nullptr, nullptr);
    bitgemm<2><<<dim3(1, NB / 8), blk, 0, stream>>>(bitsT_b, Wu3h, Wu3l, bd3, nullptr,
                                                    nullptr, out, nullptr);
}